// Round 10
// baseline (116.449 us; speedup 1.0000x reference)
//
#include <hip/hip_runtime.h>
#include <math.h>

#define S_TOT   2048
#define NNODES  128
#define D_DIM   127
#define N_STEPS 126

typedef unsigned short ushort_t;
typedef unsigned int   uint_t;
typedef __attribute__((ext_vector_type(8))) short bfrag;   // 8 bf16 = 4 VGPR
typedef __attribute__((ext_vector_type(4))) float f4;

__device__ __forceinline__ float softplus_f(float x) {
    return log1pf(expf(-fabsf(x))) + fmaxf(x, 0.0f);
}
__device__ __forceinline__ float normal_cdf_f(float x) {
    return 0.5f * (1.0f + erff(x * 0.7071067811865475f));
}
__device__ __forceinline__ float frl(float x, int lane) {
    return __int_as_float(__builtin_amdgcn_readlane(__float_as_int(x), lane));
}
// 64-lane sum via DPP; returns wave-uniform total.
__device__ __forceinline__ float wave_sum(float x) {
    float r = x; int v;
    v = __builtin_amdgcn_update_dpp(0, __float_as_int(r), 0x111, 0xf, 0xf, true); r += __int_as_float(v);
    v = __builtin_amdgcn_update_dpp(0, __float_as_int(r), 0x112, 0xf, 0xf, true); r += __int_as_float(v);
    v = __builtin_amdgcn_update_dpp(0, __float_as_int(r), 0x114, 0xf, 0xf, true); r += __int_as_float(v);
    v = __builtin_amdgcn_update_dpp(0, __float_as_int(r), 0x118, 0xf, 0xf, true); r += __int_as_float(v);
    v = __builtin_amdgcn_update_dpp(0, __float_as_int(r), 0x142, 0xa, 0xf, true); r += __int_as_float(v);
    v = __builtin_amdgcn_update_dpp(0, __float_as_int(r), 0x143, 0xc, 0xf, true); r += __int_as_float(v);
    return frl(r, 63);
}
__device__ __forceinline__ ushort_t f2bf(float x) {        // RNE fp32 -> bf16
    uint_t u = __float_as_uint(x);
    uint_t r = u + 0x7fffu + ((u >> 16) & 1u);
    return (ushort_t)(r >> 16);
}
__device__ __forceinline__ float bf2f(ushort_t h) {
    return __uint_as_float(((uint_t)h) << 16);
}

// ---------------------------------------------------------------------------
// Kernel 0: symmetrized counts packed as bf16 pair: lo = csym, hi = asym-csym
// ---------------------------------------------------------------------------
__global__ __launch_bounds__(256) void prep_counts(
        const int* __restrict__ all_t, const int* __restrict__ cor_t,
        uint_t* __restrict__ pk) {
    int i = blockIdx.x * 256 + threadIdx.x;       // 16384
    int n = i >> 7, m = i & 127;
    int at = all_t[i], ct = cor_t[i];
    if (n != m) { at += all_t[m * 128 + n]; ct += cor_t[m * 128 + n]; }
    pk[i] = (uint_t)f2bf((float)ct) | ((uint_t)f2bf((float)(at - ct)) << 16);
}

// ---------------------------------------------------------------------------
// Kernel 1: trajectory. ONE WAVE = TWO SAMPLES (A,B), steps interleaved so
// chain B's instructions statically fill chain A's dependency stalls (the
// 2-wave lockstep-correlation fix). Per-chain math identical to round 9
// (verified absmax 0.0). 1024 blocks x 1 wave; 1 wave/SIMD; 256-VGPR budget.
// ---------------------------------------------------------------------------
#define LDR1(P, DA, DB, row)                                                  \
    { const float* _p = ap##P + (size_t)(row) * D_DIM + 2 * lane;             \
      DA = _p[0];                                                             \
      float _t = _p[d1ok ? 1 : 0];   /* lane63 stays in-bounds */             \
      DB = d1ok ? _t : 0.0f; }

#define LOAD_G(P, BASE, GUARD)                                                \
    { const int _b = (BASE); const bool _gd = (GUARD);                        \
      if (!_gd || _b + 0  < 126) LDR1(P, sa##P##0,  sb##P##0,  _b + 0)  else { sa##P##0 = 0;  sb##P##0 = 0; }   \
      if (!_gd || _b + 1  < 126) LDR1(P, sa##P##1,  sb##P##1,  _b + 1)  else { sa##P##1 = 0;  sb##P##1 = 0; }   \
      if (!_gd || _b + 2  < 126) LDR1(P, sa##P##2,  sb##P##2,  _b + 2)  else { sa##P##2 = 0;  sb##P##2 = 0; }   \
      if (!_gd || _b + 3  < 126) LDR1(P, sa##P##3,  sb##P##3,  _b + 3)  else { sa##P##3 = 0;  sb##P##3 = 0; }   \
      if (!_gd || _b + 4  < 126) LDR1(P, sa##P##4,  sb##P##4,  _b + 4)  else { sa##P##4 = 0;  sb##P##4 = 0; }   \
      if (!_gd || _b + 5  < 126) LDR1(P, sa##P##5,  sb##P##5,  _b + 5)  else { sa##P##5 = 0;  sb##P##5 = 0; }   \
      if (!_gd || _b + 6  < 126) LDR1(P, sa##P##6,  sb##P##6,  _b + 6)  else { sa##P##6 = 0;  sb##P##6 = 0; }   \
      if (!_gd || _b + 7  < 126) LDR1(P, sa##P##7,  sb##P##7,  _b + 7)  else { sa##P##7 = 0;  sb##P##7 = 0; }   \
      if (!_gd || _b + 8  < 126) LDR1(P, sa##P##8,  sb##P##8,  _b + 8)  else { sa##P##8 = 0;  sb##P##8 = 0; }   \
      if (!_gd || _b + 9  < 126) LDR1(P, sa##P##9,  sb##P##9,  _b + 9)  else { sa##P##9 = 0;  sb##P##9 = 0; }   \
      if (!_gd || _b + 10 < 126) LDR1(P, sa##P##10, sb##P##10, _b + 10) else { sa##P##10 = 0; sb##P##10 = 0; }  \
      if (!_gd || _b + 11 < 126) LDR1(P, sa##P##11, sb##P##11, _b + 11) else { sa##P##11 = 0; sb##P##11 = 0; }  \
      if (!_gd || _b + 12 < 126) LDR1(P, sa##P##12, sb##P##12, _b + 12) else { sa##P##12 = 0; sb##P##12 = 0; }  \
      if (!_gd || _b + 13 < 126) LDR1(P, sa##P##13, sb##P##13, _b + 13) else { sa##P##13 = 0; sb##P##13 = 0; }  \
      if (!_gd || _b + 14 < 126) LDR1(P, sa##P##14, sb##P##14, _b + 14) else { sa##P##14 = 0; sb##P##14 = 0; }  \
      if (!_gd || _b + 15 < 126) LDR1(P, sa##P##15, sb##P##15, _b + 15) else { sa##P##15 = 0; sb##P##15 = 0; } }

#define WRITE_G(P, SB)                                                        \
    { const int _s = (SB);                                                    \
      *(float2*)&abuf##P[_s + 0 ][2 * lane] = make_float2(sa##P##0,  sb##P##0);  \
      *(float2*)&abuf##P[_s + 1 ][2 * lane] = make_float2(sa##P##1,  sb##P##1);  \
      *(float2*)&abuf##P[_s + 2 ][2 * lane] = make_float2(sa##P##2,  sb##P##2);  \
      *(float2*)&abuf##P[_s + 3 ][2 * lane] = make_float2(sa##P##3,  sb##P##3);  \
      *(float2*)&abuf##P[_s + 4 ][2 * lane] = make_float2(sa##P##4,  sb##P##4);  \
      *(float2*)&abuf##P[_s + 5 ][2 * lane] = make_float2(sa##P##5,  sb##P##5);  \
      *(float2*)&abuf##P[_s + 6 ][2 * lane] = make_float2(sa##P##6,  sb##P##6);  \
      *(float2*)&abuf##P[_s + 7 ][2 * lane] = make_float2(sa##P##7,  sb##P##7);  \
      *(float2*)&abuf##P[_s + 8 ][2 * lane] = make_float2(sa##P##8,  sb##P##8);  \
      *(float2*)&abuf##P[_s + 9 ][2 * lane] = make_float2(sa##P##9,  sb##P##9);  \
      *(float2*)&abuf##P[_s + 10][2 * lane] = make_float2(sa##P##10, sb##P##10); \
      *(float2*)&abuf##P[_s + 11][2 * lane] = make_float2(sa##P##11, sb##P##11); \
      *(float2*)&abuf##P[_s + 12][2 * lane] = make_float2(sa##P##12, sb##P##12); \
      *(float2*)&abuf##P[_s + 13][2 * lane] = make_float2(sa##P##13, sb##P##13); \
      *(float2*)&abuf##P[_s + 14][2 * lane] = make_float2(sa##P##14, sb##P##14); \
      *(float2*)&abuf##P[_s + 15][2 * lane] = make_float2(sa##P##15, sb##P##15); }

#define STEP_CORE(P, SC, SA, SR, ROWRD, CLSI, DLSI)                           \
    {                                                                         \
        const float ca = ra_r##P[SC], cb = rb_r##P[SC];                       \
        float va = wave_sum(fmaf(v0##P, ca, v1##P * cb));                     \
        float ua = fmaf(fmaf(-vp0##P, aE0U##P, va), rcp_v##P, aE0U##P);       \
        float w1 = fmaf(-ua, vp1s##P, aE1U##P);                               \
        float inv = __builtin_amdgcn_rsqf(fmaf(-va, va, aaU##P));             \
        float invs = (w1 >= 0.0f) ? -inv : inv;                               \
        float sf = sU##P * invs;                                              \
        float nv0 = fmaf(cU##P, v0##P, sf * fmaf(-va, v0##P, ca));            \
        float nv1 = fmaf(cU##P, v1##P, sf * fmaf(-va, v1##P, cb));            \
        float np0 = fmaf(cU##P, vp0##P, sf * fmaf(-va, vp0##P, aE0U##P));     \
        float np1 = fmaf(cU##P, vp1##P, sf * fmaf(-va, vp1##P, aE1U##P));     \
        v0##P = nv0; v1##P = nv1; vp0##P = np0; vp1##P = np1;                 \
        { float ns = copysignf(1.0f, vp0##P);                                 \
          rcp_v##P = __builtin_amdgcn_rcpf(vp0##P + ns);                      \
          vp1s##P = vp1##P * ns; }                                            \
        x0##P = fmaf(dU##P, v0##P, x0##P);                                    \
        x1##P = fmaf(dU##P, v1##P, x1##P);                                    \
        { uint_t pk;                                                          \
          asm("v_cvt_pk_bf16_f32 %0, %1, %2"                                  \
              : "=v"(pk) : "v"(x0##P), "v"(x1##P));                           \
          xp##P += 64; xp##P[lane] = pk; }                                    \
        aaU##P = aa1##P; aE0U##P = aE0_1##P; aE1U##P = aE1_1##P;              \
        cU##P = c1##P; sU##P = s1##P; dU##P = d1##P;                          \
        aa1##P = wave_sum(fmaf(ra_r##P[SA], ra_r##P[SA],                      \
                               rb_r##P[SA] * rb_r##P[SA]));                   \
        aE0_1##P = frl(ra_r##P[SA], 0); aE1_1##P = frl(rb_r##P[SA], 0);       \
        { float2 cs = cls2##P[CLSI]; c1##P = cs.x; s1##P = cs.y; }            \
        d1##P = dls##P[DLSI];                                                 \
        { float2 nx = *(float2*)&abuf##P[ROWRD][2 * lane];                    \
          ra_r##P[SR] = nx.x; rb_r##P[SR] = nx.y; }                           \
    }

#define MSTEP(J)                                                              \
    STEP_CORE(A, (J) & 3, ((J) + 2) & 3, ((J) + 3) & 3,                       \
              (ib + (J) + 3) & 31, ib + (J) + 2, ib + (J) + 3)                \
    STEP_CORE(B, (J) & 3, ((J) + 2) & 3, ((J) + 3) & 3,                       \
              (ib + (J) + 3) & 31, ib + (J) + 2, ib + (J) + 3)
#define TSTEP(J)                                                              \
    STEP_CORE(A, (J) & 3, ((J) + 2) & 3, ((J) + 3) & 3,                       \
              ((115 + (J) < 125) ? (115 + (J)) : 125) & 31,                   \
              ((114 + (J) < 127) ? (114 + (J)) : 127),                        \
              ((115 + (J) < 127) ? (115 + (J)) : 127))                        \
    STEP_CORE(B, (J) & 3, ((J) + 2) & 3, ((J) + 3) & 3,                       \
              ((115 + (J) < 125) ? (115 + (J)) : 125) & 31,                   \
              ((114 + (J) < 127) ? (114 + (J)) : 127),                        \
              ((115 + (J) < 127) ? (115 + (J)) : 127))

#define DECL_CHAIN(P)                                                         \
    float sa##P##0, sa##P##1, sa##P##2, sa##P##3, sa##P##4, sa##P##5,         \
          sa##P##6, sa##P##7, sa##P##8, sa##P##9, sa##P##10, sa##P##11,       \
          sa##P##12, sa##P##13, sa##P##14, sa##P##15;                         \
    float sb##P##0, sb##P##1, sb##P##2, sb##P##3, sb##P##4, sb##P##5,         \
          sb##P##6, sb##P##7, sb##P##8, sb##P##9, sb##P##10, sb##P##11,       \
          sb##P##12, sb##P##13, sb##P##14, sb##P##15;                         \
    float ra_r##P[4], rb_r##P[4];                                             \
    float aaU##P, aa1##P, aE0U##P, aE1U##P, aE0_1##P, aE1_1##P;               \
    float cU##P, sU##P, c1##P, s1##P, dU##P, d1##P;                           \
    float v0##P, v1##P, vp0##P, vp1##P, vp1s##P, rcp_v##P;                    \
    float x0##P, x1##P;                                                       \
    uint_t* xp##P;

#define INIT_CHAIN(P, SIDX, LIDX)                                             \
    {                                                                         \
        float t0 = softplus_f(d_raw[(size_t)(SIDX) * D_DIM + lane]);          \
        dls##P[lane] = t0;                                                    \
        dls##P[64 + lane] = d1ok ?                                            \
            softplus_f(d_raw[(size_t)(SIDX) * D_DIM + 64 + lane]) : 0.0f;     \
        float cv = c_raw[(size_t)(SIDX) * N_STEPS + lane];                    \
        cls2##P[lane] = make_float2(__cosf(cv), __sinf(cv));                  \
        if (lane < 62) {                                                      \
            float cv2 = c_raw[(size_t)(SIDX) * N_STEPS + 64 + lane];          \
            cls2##P[64 + lane] = make_float2(__cosf(cv2), __sinf(cv2));       \
        } else {                                                              \
            cls2##P[64 + lane] = make_float2(0.0f, 0.0f);                     \
        }                                                                     \
        v0##P = (lane == 0) ? 1.0f : 0.0f; v1##P = 0.0f;                      \
        vp0##P = 1.0f; vp1##P = 0.0f; vp1s##P = 0.0f; rcp_v##P = 0.5f;        \
        x0##P = (lane == 0) ? t0 : 0.0f; x1##P = 0.0f;                        \
        xp##P = xout + (size_t)(LIDX) * NNODES * 64;                          \
        xp##P[lane] = 0u;                                                     \
        uint_t pk0;                                                           \
        asm("v_cvt_pk_bf16_f32 %0, %1, %2"                                    \
            : "=v"(pk0) : "v"(x0##P), "v"(x1##P));                            \
        xp##P += 64; xp##P[lane] = pk0;                                       \
    }

#define PRIME_CHAIN(P)                                                        \
    { float2 t = *(float2*)&abuf##P[0][2 * lane];                             \
      ra_r##P[0] = t.x; rb_r##P[0] = t.y; }                                   \
    { float2 t = *(float2*)&abuf##P[1][2 * lane];                             \
      ra_r##P[1] = t.x; rb_r##P[1] = t.y; }                                   \
    { float2 t = *(float2*)&abuf##P[2][2 * lane];                             \
      ra_r##P[2] = t.x; rb_r##P[2] = t.y; }                                   \
    ra_r##P[3] = 0.0f; rb_r##P[3] = 0.0f;                                     \
    aaU##P = wave_sum(fmaf(ra_r##P[0], ra_r##P[0], rb_r##P[0] * rb_r##P[0])); \
    aa1##P = wave_sum(fmaf(ra_r##P[1], ra_r##P[1], rb_r##P[1] * rb_r##P[1])); \
    aE0U##P = frl(ra_r##P[0], 0); aE1U##P = frl(rb_r##P[0], 0);               \
    aE0_1##P = frl(ra_r##P[1], 0); aE1_1##P = frl(rb_r##P[1], 0);             \
    { float2 cs = cls2##P[0]; cU##P = cs.x; sU##P = cs.y; }                   \
    { float2 cs = cls2##P[1]; c1##P = cs.x; s1##P = cs.y; }                   \
    dU##P = dls##P[1]; d1##P = dls##P[2];

__global__
__attribute__((amdgpu_flat_work_group_size(64, 64), amdgpu_waves_per_eu(1, 1)))
void traj_kernel(
        const float* __restrict__ d_raw, const float* __restrict__ c_raw,
        const float* __restrict__ a_raw,
        uint_t* __restrict__ xout, int s_base) {
    const int li = blockIdx.x;                    // block handles samples 2li, 2li+1
    const int sA = s_base + 2 * li;
    const int sB = sA + 1;
    const int lane = threadIdx.x;
    const bool d1ok = lane < 63;                  // dim 2l+1 <= 126

    __shared__ __align__(16) float abufA[32][128];   // 16 KB
    __shared__ __align__(16) float abufB[32][128];   // 16 KB
    __shared__ float  dlsA[128], dlsB[128];
    __shared__ float2 cls2A[128], cls2B[128];

    const float* apA = a_raw + (size_t)sA * N_STEPS * D_DIM;
    const float* apB = a_raw + (size_t)sB * N_STEPS * D_DIM;

    DECL_CHAIN(A)
    DECL_CHAIN(B)

    INIT_CHAIN(A, sA, 2 * li)
    INIT_CHAIN(B, sB, 2 * li + 1)

    // prologue staging: G0,G1 written; G2 loaded (written at boundary g=0)
    LOAD_G(A, 0, false)  WRITE_G(A, 0)
    LOAD_G(B, 0, false)  WRITE_G(B, 0)
    LOAD_G(A, 16, false) WRITE_G(A, 16)
    LOAD_G(B, 16, false) WRITE_G(B, 16)
    LOAD_G(A, 32, false)
    LOAD_G(B, 32, false)

    PRIME_CHAIN(A)
    PRIME_CHAIN(B)

    // main: 7 groups x 16 steps (i = 0..111), chains A,B interleaved
    #pragma unroll 1
    for (int g = 0; g < 7; ++g) {
        const int ib = g << 4;
        MSTEP(0)  MSTEP(1)  MSTEP(2)  MSTEP(3)
        MSTEP(4)  MSTEP(5)  MSTEP(6)  MSTEP(7)
        MSTEP(8)  MSTEP(9)  MSTEP(10) MSTEP(11)
        MSTEP(12) MSTEP(13) MSTEP(14) MSTEP(15)
        if (g <= 5) { WRITE_G(A, (g & 1) << 4) WRITE_G(B, (g & 1) << 4) }
        if (g <= 4) { LOAD_G(A, (g + 3) << 4, g == 4)
                      LOAD_G(B, (g + 3) << 4, g == 4) }
    }
    // tail: steps 112..125
    TSTEP(0)  TSTEP(1)  TSTEP(2)  TSTEP(3)
    TSTEP(4)  TSTEP(5)  TSTEP(6)  TSTEP(7)
    TSTEP(8)  TSTEP(9)  TSTEP(10) TSTEP(11)
    TSTEP(12) TSTEP(13)
}
#undef MSTEP
#undef TSTEP
#undef STEP_CORE
#undef LOAD_G
#undef WRITE_G
#undef LDR1
#undef DECL_CHAIN
#undef INIT_CHAIN
#undef PRIME_CHAIN

// ---------------------------------------------------------------------------
// Kernel 2: MFMA gram (single 32KB bf16 LDS stage) + B-S tail log-lik.
// 4 waves; wave w owns tile-rows {w, 7-w} via template<int W> (acc = 9 f4).
// ---------------------------------------------------------------------------
__device__ __forceinline__ bfrag ldfrag(const ushort_t* base, int row, int kelem) {
    int byte = ((row << 8) + (kelem << 1)) ^ ((row & 7) << 4);
    return *(const bfrag*)((const char*)base + byte);
}

template<int W>
__device__ __forceinline__ void gram_w(const ushort_t* Xs, f4 (&acc)[9],
                                       int lr, int lg) {
    constexpr int RA = W, RB = 7 - W;
    #pragma unroll
    for (int ks = 0; ks < 4; ++ks) {
        const int kb = ks * 32 + lg * 8;
        const bfrag ha = ldfrag(Xs, RA * 16 + lr, kb);
        const bfrag hb = ldfrag(Xs, RB * 16 + lr, kb);
        #pragma unroll
        for (int TC = W; TC < 8; ++TC) {
            const bfrag bh = ldfrag(Xs, TC * 16 + lr, kb);
            acc[TC - W] = __builtin_amdgcn_mfma_f32_16x16x32_bf16(ha, bh, acc[TC - W], 0, 0, 0);
            if (TC >= RB)
                acc[TC + 1] = __builtin_amdgcn_mfma_f32_16x16x32_bf16(hb, bh, acc[TC + 1], 0, 0, 0);
        }
    }
}

template<int W>
__device__ __forceinline__ void write_sq(const f4 (&acc)[9], float* sq, int lr, int lg) {
    #pragma unroll
    for (int q = 0; q < 4; ++q) {
        if (4 * lg + q == lr) {
            sq[W * 16 + lr]       = acc[0][q];       // tile (W,W)
            sq[(7 - W) * 16 + lr] = acc[8 - W][q];   // tile (7-W,7-W)
        }
    }
}

// Borjesson-Sundberg Q(z) ~ phi(z)/((1-A)z + A*sqrt(z^2+B)); rel err <~0.5%.
// q_axb = F1 + F2 - 2 F1 F2 is relative-accurate (no cancellation).
__device__ __forceinline__ float entry_ll(float g, float sqn, float sqm,
        uint_t cw, float lam, float one_m2l) {
    const float d2 = fmaxf(sqn + sqm - 2.0f * g, 0.0f);
    const float pd = __builtin_amdgcn_sqrtf(d2);
    const float A = 0.344f, B = 5.334f, IA = 0.656f, C = 0.3989422804f;
    const float z1 = 0.70710678f * pd, z2 = 0.5f * pd;
    const float e1 = __expf(-0.25f  * d2) * C;   // phi(z1)
    const float e2 = __expf(-0.125f * d2) * C;   // phi(z2)
    const float den1 = fmaf(A, __builtin_amdgcn_sqrtf(fmaf(0.5f,  d2, B)), IA * z1);
    const float den2 = fmaf(A, __builtin_amdgcn_sqrtf(fmaf(0.25f, d2, B)), IA * z2);
    const float F1 = e1 * __builtin_amdgcn_rcpf(den1);
    const float F2 = e2 * __builtin_amdgcn_rcpf(den2);
    const float qax = F1 + F2 - 2.0f * F1 * F2;
    float qp = fmaf(one_m2l, qax, lam);
    qp = fminf(fmaxf(qp, 1e-7f), 1.0f - 1e-7f);
    const float pp = 1.0f - qp;
    const float c   = bf2f((ushort_t)(cw & 0xffffu));
    const float amc = bf2f((ushort_t)(cw >> 16));
    return c * __logf(pp) + amc * __logf(qp);
}

__device__ __forceinline__ float tile_ll(f4 a, int TR, int TC, bool diag,
        int lr, int lg, const float* sq, const uint_t* __restrict__ cnt,
        float lam, float one_m2l) {
    float s = 0.0f;
    #pragma unroll
    for (int q = 0; q < 4; ++q) {
        const int n = TR * 16 + 4 * lg + q;
        const int m = TC * 16 + lr;
        if (!diag || (4 * lg + q) <= lr)
            s += entry_ll(a[q], sq[n], sq[m], cnt[n * 128 + m], lam, one_m2l);
    }
    return s;
}

template<int W>
__device__ __forceinline__ float epi(const f4 (&acc)[9], const float* sq,
        const uint_t* __restrict__ cnt, int lr, int lg, float lam, float one_m2l) {
    constexpr int RA = W, RB = 7 - W;
    float s = 0.0f;
    #pragma unroll
    for (int TC = W; TC < 8; ++TC) {
        s += tile_ll(acc[TC - W], RA, TC, (TC == RA), lr, lg, sq, cnt, lam, one_m2l);
        if (TC >= RB)
            s += tile_ll(acc[TC + 1], RB, TC, (TC == RB), lr, lg, sq, cnt, lam, one_m2l);
    }
    return s;
}

__global__ __launch_bounds__(256, 4) void ll_kernel(
        const uint_t* __restrict__ x_g,
        const float* __restrict__ l_raw, const uint_t* __restrict__ cnt,
        float* __restrict__ sums, int s_base) {
    const int li = blockIdx.x;
    const int s  = s_base + li;
    const int t  = threadIdx.x;

    __shared__ __align__(16) ushort_t Xs[NNODES * 128];   // 32 KB
    __shared__ float sq[NNODES];
    __shared__ float wsum[4];

    const uint_t* gx = x_g + (size_t)li * NNODES * 64;
    const int l = t & 63, w = t >> 6, lr = l & 15, lg = l >> 4;

    // fill LDS (swizzled) with 16B chunks; 2048 chunks over 256 threads
    #pragma unroll
    for (int ii = 0; ii < 8; ++ii) {
        const int i = t + ii * 256;
        const int row = i >> 4, j = i & 15;
        const uint4 v = *(const uint4*)(gx + row * 64 + j * 4);
        const int b = ((row << 8) + (j << 4)) ^ ((row & 7) << 4);
        *(uint4*)((char*)Xs + b) = v;
    }
    __syncthreads();

    f4 acc[9];
    #pragma unroll
    for (int i = 0; i < 9; ++i) acc[i] = (f4)(0.0f);

    switch (w) {
        case 0: gram_w<0>(Xs, acc, lr, lg); write_sq<0>(acc, sq, lr, lg); break;
        case 1: gram_w<1>(Xs, acc, lr, lg); write_sq<1>(acc, sq, lr, lg); break;
        case 2: gram_w<2>(Xs, acc, lr, lg); write_sq<2>(acc, sq, lr, lg); break;
        default: gram_w<3>(Xs, acc, lr, lg); write_sq<3>(acc, sq, lr, lg); break;
    }
    __syncthreads();

    const float lam = 0.06f * normal_cdf_f(l_raw[s]);
    const float one_m2l = 1.0f - 2.0f * lam;
    float ll = 0.0f;
    switch (w) {
        case 0: ll = epi<0>(acc, sq, cnt, lr, lg, lam, one_m2l); break;
        case 1: ll = epi<1>(acc, sq, cnt, lr, lg, lam, one_m2l); break;
        case 2: ll = epi<2>(acc, sq, cnt, lr, lg, lam, one_m2l); break;
        default: ll = epi<3>(acc, sq, cnt, lr, lg, lam, one_m2l); break;
    }

    const float wtot = wave_sum(ll);
    if (l == 0) wsum[w] = wtot;
    __syncthreads();
    if (t == 0) sums[s] = wsum[0] + wsum[1] + wsum[2] + wsum[3];
}

// ---------------------------------------------------------------------------
// Kernel 3: deterministic mean over S
// ---------------------------------------------------------------------------
__global__ __launch_bounds__(256) void reduce_kernel(
        const float* __restrict__ sums, float* __restrict__ out) {
    __shared__ double sh[256];
    const int t = threadIdx.x;
    double acc = 0.0;
    for (int i = t; i < S_TOT; i += 256) acc += (double)sums[i];
    sh[t] = acc;
    __syncthreads();
    for (int off = 128; off > 0; off >>= 1) {
        if (t < off) sh[t] += sh[t + off];
        __syncthreads();
    }
    if (t == 0) out[0] = (float)(sh[0] / (double)S_TOT);
}

// ---------------------------------------------------------------------------
extern "C" void kernel_launch(void* const* d_in, const int* in_sizes, int n_in,
                              void* d_out, int out_size, void* d_ws, size_t ws_size,
                              hipStream_t stream) {
    (void)in_sizes; (void)n_in; (void)out_size;
    const float* d_raw = (const float*)d_in[0];
    const float* c_raw = (const float*)d_in[1];
    const float* a_raw = (const float*)d_in[2];
    const float* l_raw = (const float*)d_in[3];
    const int*   all_t = (const int*)d_in[4];
    const int*   cor_t = (const int*)d_in[5];
    float* out = (float*)d_out;

    char*   ws   = (char*)d_ws;
    float*  sums = (float*)ws;                        // 8 KB
    uint_t* cnt  = (uint_t*)(ws + 8192);              // 64 KB packed counts
    char*   xbase = ws + 8192 + 65536;
    const size_t per_sample = (size_t)NNODES * 64 * sizeof(uint_t);  // 32 KB

    const size_t head = 8192 + 65536;
    size_t avail = (ws_size > head) ? ws_size - head : 0;
    int chunk = (int)(avail / per_sample);
    if (chunk > S_TOT) chunk = S_TOT;
    chunk &= ~1;                                      // traj handles sample pairs
    if (chunk < 2) chunk = 2;

    prep_counts<<<64, 256, 0, stream>>>(all_t, cor_t, cnt);

    for (int s0 = 0; s0 < S_TOT; s0 += chunk) {
        const int nblk = (S_TOT - s0 < chunk) ? (S_TOT - s0) : chunk;
        uint_t* xbuf = (uint_t*)xbase;
        traj_kernel<<<nblk / 2, 64, 0, stream>>>(d_raw, c_raw, a_raw, xbuf, s0);
        ll_kernel<<<nblk, 256, 0, stream>>>(xbuf, l_raw, cnt, sums, s0);
    }
    reduce_kernel<<<1, 256, 0, stream>>>(sums, out);
}

// Round 11
// 100.983 us; speedup vs baseline: 1.1532x; 1.1532x over previous
//
#include <hip/hip_runtime.h>
#include <math.h>

#define S_TOT   2048
#define NNODES  128
#define D_DIM   127
#define N_STEPS 126

typedef unsigned short ushort_t;
typedef unsigned int   uint_t;
typedef __attribute__((ext_vector_type(8))) short bfrag;   // 8 bf16 = 4 VGPR
typedef __attribute__((ext_vector_type(4))) float f4;

__device__ __forceinline__ float softplus_f(float x) {
    return log1pf(expf(-fabsf(x))) + fmaxf(x, 0.0f);
}
__device__ __forceinline__ float normal_cdf_f(float x) {
    return 0.5f * (1.0f + erff(x * 0.7071067811865475f));
}
__device__ __forceinline__ float frl(float x, int lane) {
    return __int_as_float(__builtin_amdgcn_readlane(__float_as_int(x), lane));
}
// 64-lane sum via DPP; returns wave-uniform total.
__device__ __forceinline__ float wave_sum(float x) {
    float r = x; int v;
    v = __builtin_amdgcn_update_dpp(0, __float_as_int(r), 0x111, 0xf, 0xf, true); r += __int_as_float(v);
    v = __builtin_amdgcn_update_dpp(0, __float_as_int(r), 0x112, 0xf, 0xf, true); r += __int_as_float(v);
    v = __builtin_amdgcn_update_dpp(0, __float_as_int(r), 0x114, 0xf, 0xf, true); r += __int_as_float(v);
    v = __builtin_amdgcn_update_dpp(0, __float_as_int(r), 0x118, 0xf, 0xf, true); r += __int_as_float(v);
    v = __builtin_amdgcn_update_dpp(0, __float_as_int(r), 0x142, 0xa, 0xf, true); r += __int_as_float(v);
    v = __builtin_amdgcn_update_dpp(0, __float_as_int(r), 0x143, 0xc, 0xf, true); r += __int_as_float(v);
    return frl(r, 63);
}
__device__ __forceinline__ ushort_t f2bf(float x) {        // RNE fp32 -> bf16
    uint_t u = __float_as_uint(x);
    uint_t r = u + 0x7fffu + ((u >> 16) & 1u);
    return (ushort_t)(r >> 16);
}
__device__ __forceinline__ float bf2f(ushort_t h) {
    return __uint_as_float(((uint_t)h) << 16);
}

// ---------------------------------------------------------------------------
// Kernel 0: symmetrized counts packed as bf16 pair: lo = csym, hi = asym-csym
// ---------------------------------------------------------------------------
__global__ __launch_bounds__(256) void prep_counts(
        const int* __restrict__ all_t, const int* __restrict__ cor_t,
        uint_t* __restrict__ pk) {
    int i = blockIdx.x * 256 + threadIdx.x;       // 16384
    int n = i >> 7, m = i & 127;
    int at = all_t[i], ct = cor_t[i];
    if (n != m) { at += all_t[m * 128 + n]; ct += cor_t[m * 128 + n]; }
    pk[i] = (uint_t)f2bf((float)ct) | ((uint_t)f2bf((float)(at - ct)) << 16);
}

// ---------------------------------------------------------------------------
// Kernel 1: trajectory. One wave per sample; lane l owns dims 2l, 2l+1.
// Round-9 structure EXCEPT the x output path: per-step global stores
// (vmcnt wait every step) are replaced by ds_write into a 2KB LDS staging
// ring, flushed as coalesced dwordx4 stores every 8 steps (vmcnt reuse
// distance = 8 steps, fully covered by compute).
// ---------------------------------------------------------------------------
#define LDR1(A, B, row)                                                       \
    { const float* _p = ap + (size_t)(row) * D_DIM + 2 * lane;                \
      A = _p[0];                                                              \
      float _t = _p[d1ok ? 1 : 0];   /* lane63 stays in-bounds */             \
      B = d1ok ? _t : 0.0f; }

#define LOAD_G(BASE, GUARD)                                                   \
    { const int _b = (BASE); const bool _gd = (GUARD);                        \
      if (!_gd || _b + 0  < 126) LDR1(sa0,  sb0,  _b + 0)  else { sa0 = 0; sb0 = 0; }   \
      if (!_gd || _b + 1  < 126) LDR1(sa1,  sb1,  _b + 1)  else { sa1 = 0; sb1 = 0; }   \
      if (!_gd || _b + 2  < 126) LDR1(sa2,  sb2,  _b + 2)  else { sa2 = 0; sb2 = 0; }   \
      if (!_gd || _b + 3  < 126) LDR1(sa3,  sb3,  _b + 3)  else { sa3 = 0; sb3 = 0; }   \
      if (!_gd || _b + 4  < 126) LDR1(sa4,  sb4,  _b + 4)  else { sa4 = 0; sb4 = 0; }   \
      if (!_gd || _b + 5  < 126) LDR1(sa5,  sb5,  _b + 5)  else { sa5 = 0; sb5 = 0; }   \
      if (!_gd || _b + 6  < 126) LDR1(sa6,  sb6,  _b + 6)  else { sa6 = 0; sb6 = 0; }   \
      if (!_gd || _b + 7  < 126) LDR1(sa7,  sb7,  _b + 7)  else { sa7 = 0; sb7 = 0; }   \
      if (!_gd || _b + 8  < 126) LDR1(sa8,  sb8,  _b + 8)  else { sa8 = 0; sb8 = 0; }   \
      if (!_gd || _b + 9  < 126) LDR1(sa9,  sb9,  _b + 9)  else { sa9 = 0; sb9 = 0; }   \
      if (!_gd || _b + 10 < 126) LDR1(sa10, sb10, _b + 10) else { sa10 = 0; sb10 = 0; } \
      if (!_gd || _b + 11 < 126) LDR1(sa11, sb11, _b + 11) else { sa11 = 0; sb11 = 0; } \
      if (!_gd || _b + 12 < 126) LDR1(sa12, sb12, _b + 12) else { sa12 = 0; sb12 = 0; } \
      if (!_gd || _b + 13 < 126) LDR1(sa13, sb13, _b + 13) else { sa13 = 0; sb13 = 0; } \
      if (!_gd || _b + 14 < 126) LDR1(sa14, sb14, _b + 14) else { sa14 = 0; sb14 = 0; } \
      if (!_gd || _b + 15 < 126) LDR1(sa15, sb15, _b + 15) else { sa15 = 0; sb15 = 0; } }

#define WRITE_G(SB)                                                           \
    { const int _s = (SB);                                                    \
      *(float2*)&abuf[_s + 0 ][2 * lane] = make_float2(sa0,  sb0);            \
      *(float2*)&abuf[_s + 1 ][2 * lane] = make_float2(sa1,  sb1);            \
      *(float2*)&abuf[_s + 2 ][2 * lane] = make_float2(sa2,  sb2);            \
      *(float2*)&abuf[_s + 3 ][2 * lane] = make_float2(sa3,  sb3);            \
      *(float2*)&abuf[_s + 4 ][2 * lane] = make_float2(sa4,  sb4);            \
      *(float2*)&abuf[_s + 5 ][2 * lane] = make_float2(sa5,  sb5);            \
      *(float2*)&abuf[_s + 6 ][2 * lane] = make_float2(sa6,  sb6);            \
      *(float2*)&abuf[_s + 7 ][2 * lane] = make_float2(sa7,  sb7);            \
      *(float2*)&abuf[_s + 8 ][2 * lane] = make_float2(sa8,  sb8);            \
      *(float2*)&abuf[_s + 9 ][2 * lane] = make_float2(sa9,  sb9);            \
      *(float2*)&abuf[_s + 10][2 * lane] = make_float2(sa10, sb10);           \
      *(float2*)&abuf[_s + 11][2 * lane] = make_float2(sa11, sb11);           \
      *(float2*)&abuf[_s + 12][2 * lane] = make_float2(sa12, sb12);           \
      *(float2*)&abuf[_s + 13][2 * lane] = make_float2(sa13, sb13);           \
      *(float2*)&abuf[_s + 14][2 * lane] = make_float2(sa14, sb14);           \
      *(float2*)&abuf[_s + 15][2 * lane] = make_float2(sa15, sb15); }

// I: step index (wave-uniform); SC/SA/SR: ring slots; ROWRD: abuf refill row;
// CLSI/DLSI: cos-sin / dstep lookahead; FLUSH: write 8 staged rows to global.
#define STEP_CORE(I, SC, SA, SR, ROWRD, CLSI, DLSI, FLUSH)                    \
    {                                                                         \
        const float ca = ra_r[SC], cb = rb_r[SC];                             \
        float va = wave_sum(fmaf(v0, ca, v1 * cb));                           \
        float ua = fmaf(fmaf(-vp0, aE0U, va), rcp_v, aE0U);                   \
        float w1 = fmaf(-ua, vp1s, aE1U);                                     \
        float inv = __builtin_amdgcn_rsqf(fmaf(-va, va, aaU));                \
        float invs = (w1 >= 0.0f) ? -inv : inv;                               \
        float sf = sU * invs;                                                 \
        float nv0 = fmaf(cU, v0, sf * fmaf(-va, v0, ca));                     \
        float nv1 = fmaf(cU, v1, sf * fmaf(-va, v1, cb));                     \
        float np0 = fmaf(cU, vp0, sf * fmaf(-va, vp0, aE0U));                 \
        float np1 = fmaf(cU, vp1, sf * fmaf(-va, vp1, aE1U));                 \
        v0 = nv0; v1 = nv1; vp0 = np0; vp1 = np1;                             \
        { float ns = copysignf(1.0f, vp0);                                    \
          rcp_v = __builtin_amdgcn_rcpf(vp0 + ns); vp1s = vp1 * ns; }         \
        x0 = fmaf(dU, v0, x0); x1 = fmaf(dU, v1, x1);                         \
        { uint_t pk;                                                          \
          asm("v_cvt_pk_bf16_f32 %0, %1, %2" : "=v"(pk) : "v"(x0), "v"(x1));  \
          xstage[(((I) + 2) & 7) * 64 + lane] = pk; }   /* ds_write, no vmcnt */ \
        aaU = aa1; aE0U = aE0_1; aE1U = aE1_1; cU = c1; sU = s1; dU = d1;     \
        aa1 = wave_sum(fmaf(ra_r[SA], ra_r[SA], rb_r[SA] * rb_r[SA]));        \
        aE0_1 = frl(ra_r[SA], 0); aE1_1 = frl(rb_r[SA], 0);                   \
        { float2 cs = cls2[CLSI]; c1 = cs.x; s1 = cs.y; }                     \
        d1 = dls[DLSI];                                                       \
        { float2 nx = *(float2*)&abuf[ROWRD][2 * lane];                       \
          ra_r[SR] = nx.x; rb_r[SR] = nx.y; }                                 \
        if (FLUSH) {   /* rows (I-5)..(I+2); slots linear since I%8==5 */     \
            uint4 t0 = *(uint4*)&xstage[4 * lane];                            \
            uint4 t1 = *(uint4*)&xstage[256 + 4 * lane];                      \
            uint_t* dst = xg + ((I) - 5) * 64;                                \
            *(uint4*)(dst + 4 * lane) = t0;                                   \
            *(uint4*)(dst + 256 + 4 * lane) = t1;                             \
        }                                                                     \
    }

#define MSTEP(J) STEP_CORE(ib + (J), (J) & 3, ((J) + 2) & 3, ((J) + 3) & 3,   \
                           (ib + (J) + 3) & 31, ib + (J) + 2, ib + (J) + 3,   \
                           ((J) == 5 || (J) == 13))
#define TSTEP(J) STEP_CORE(112 + (J), (J) & 3, ((J) + 2) & 3, ((J) + 3) & 3,  \
                           ((115 + (J) < 125) ? (115 + (J)) : 125) & 31,      \
                           ((114 + (J) < 127) ? (114 + (J)) : 127),           \
                           ((115 + (J) < 127) ? (115 + (J)) : 127),           \
                           ((J) == 5 || (J) == 13))

__global__
__attribute__((amdgpu_flat_work_group_size(64, 64), amdgpu_waves_per_eu(2, 2)))
void traj_kernel(
        const float* __restrict__ d_raw, const float* __restrict__ c_raw,
        const float* __restrict__ a_raw,
        uint_t* __restrict__ xout, int s_base) {
    const int li = blockIdx.x;
    const int s  = s_base + li;
    const int lane = threadIdx.x;
    const bool d1ok = lane < 63;                  // dim 2l+1 <= 126

    __shared__ __align__(16) float abuf[32][128]; // 16 KB (2 groups x 16 rows)
    __shared__ __align__(16) uint_t xstage[512];  // 2 KB (8 x-rows)
    __shared__ float  dls[128];
    __shared__ float2 cls2[128];

    // d (softplus'd), cos/sin tables for uniform broadcast reads (padded 0)
    float t0 = softplus_f(d_raw[(size_t)s * D_DIM + lane]);
    dls[lane] = t0;
    dls[64 + lane] = d1ok ? softplus_f(d_raw[(size_t)s * D_DIM + 64 + lane]) : 0.0f;
    {
        float cv = c_raw[(size_t)s * N_STEPS + lane];
        cls2[lane] = make_float2(__cosf(cv), __sinf(cv));
        if (lane < 62) {
            float cv2 = c_raw[(size_t)s * N_STEPS + 64 + lane];
            cls2[64 + lane] = make_float2(__cosf(cv2), __sinf(cv2));
        } else {
            cls2[64 + lane] = make_float2(0.0f, 0.0f);
        }
    }

    const float* ap = a_raw + (size_t)s * N_STEPS * D_DIM;
    uint_t* xg = xout + (size_t)li * NNODES * 64;

    // staging regs: one 16-row group
    float sa0, sa1, sa2, sa3, sa4, sa5, sa6, sa7,
          sa8, sa9, sa10, sa11, sa12, sa13, sa14, sa15;
    float sb0, sb1, sb2, sb3, sb4, sb5, sb6, sb7,
          sb8, sb9, sb10, sb11, sb12, sb13, sb14, sb15;

    // prologue: G0,G1 staged+written; G2 loaded (written at boundary g=0)
    LOAD_G(0, false)  WRITE_G(0)
    LOAD_G(16, false) WRITE_G(16)
    LOAD_G(32, false)

    // ring (rows i..i+3) + pipelines primed for steps 0,1
    float ra_r[4], rb_r[4];
    { float2 t = *(float2*)&abuf[0][2 * lane]; ra_r[0] = t.x; rb_r[0] = t.y; }
    { float2 t = *(float2*)&abuf[1][2 * lane]; ra_r[1] = t.x; rb_r[1] = t.y; }
    { float2 t = *(float2*)&abuf[2][2 * lane]; ra_r[2] = t.x; rb_r[2] = t.y; }
    ra_r[3] = 0.0f; rb_r[3] = 0.0f;
    float aaU = wave_sum(fmaf(ra_r[0], ra_r[0], rb_r[0] * rb_r[0]));
    float aa1 = wave_sum(fmaf(ra_r[1], ra_r[1], rb_r[1] * rb_r[1]));
    float aE0U = frl(ra_r[0], 0), aE1U = frl(rb_r[0], 0);
    float aE0_1 = frl(ra_r[1], 0), aE1_1 = frl(rb_r[1], 0);
    float cU, sU, c1, s1;
    { float2 cs = cls2[0]; cU = cs.x; sU = cs.y; }
    { float2 cs = cls2[1]; c1 = cs.x; s1 = cs.y; }
    float dU = dls[1], d1 = dls[2];

    // state: v (lane dims), replicated pivots, x
    float v0 = (lane == 0) ? 1.0f : 0.0f, v1 = 0.0f;
    float vp0 = 1.0f, vp1 = 0.0f, vp1s = 0.0f, rcp_v = 0.5f;
    float x0 = (lane == 0) ? t0 : 0.0f, x1 = 0.0f;

    // x rows 0,1 into staging slots 0,1
    xstage[lane] = 0u;
    {
        uint_t pk0;
        asm("v_cvt_pk_bf16_f32 %0, %1, %2" : "=v"(pk0) : "v"(x0), "v"(x1));
        xstage[64 + lane] = pk0;
    }

    // main: 7 groups x 16 steps (i = 0..111)
    #pragma unroll 1
    for (int g = 0; g < 7; ++g) {
        const int ib = g << 4;
        MSTEP(0)  MSTEP(1)  MSTEP(2)  MSTEP(3)
        MSTEP(4)  MSTEP(5)  MSTEP(6)  MSTEP(7)
        MSTEP(8)  MSTEP(9)  MSTEP(10) MSTEP(11)
        MSTEP(12) MSTEP(13) MSTEP(14) MSTEP(15)
        if (g <= 5) { WRITE_G((g & 1) << 4) }     // write G_{g+2}
        if (g <= 4) LOAD_G((g + 3) << 4, g == 4)  // load  G_{g+3}
    }
    // tail: steps 112..125 (flushes at 117 and 125 cover rows 112..127)
    TSTEP(0)  TSTEP(1)  TSTEP(2)  TSTEP(3)
    TSTEP(4)  TSTEP(5)  TSTEP(6)  TSTEP(7)
    TSTEP(8)  TSTEP(9)  TSTEP(10) TSTEP(11)
    TSTEP(12) TSTEP(13)
}
#undef MSTEP
#undef TSTEP
#undef STEP_CORE
#undef LOAD_G
#undef WRITE_G
#undef LDR1

// ---------------------------------------------------------------------------
// Kernel 2: MFMA gram (single 32KB bf16 LDS stage) + B-S tail log-lik.
// 4 waves; wave w owns tile-rows {w, 7-w} via template<int W> (acc = 9 f4).
// ---------------------------------------------------------------------------
__device__ __forceinline__ bfrag ldfrag(const ushort_t* base, int row, int kelem) {
    int byte = ((row << 8) + (kelem << 1)) ^ ((row & 7) << 4);
    return *(const bfrag*)((const char*)base + byte);
}

template<int W>
__device__ __forceinline__ void gram_w(const ushort_t* Xs, f4 (&acc)[9],
                                       int lr, int lg) {
    constexpr int RA = W, RB = 7 - W;
    #pragma unroll
    for (int ks = 0; ks < 4; ++ks) {
        const int kb = ks * 32 + lg * 8;
        const bfrag ha = ldfrag(Xs, RA * 16 + lr, kb);
        const bfrag hb = ldfrag(Xs, RB * 16 + lr, kb);
        #pragma unroll
        for (int TC = W; TC < 8; ++TC) {
            const bfrag bh = ldfrag(Xs, TC * 16 + lr, kb);
            acc[TC - W] = __builtin_amdgcn_mfma_f32_16x16x32_bf16(ha, bh, acc[TC - W], 0, 0, 0);
            if (TC >= RB)
                acc[TC + 1] = __builtin_amdgcn_mfma_f32_16x16x32_bf16(hb, bh, acc[TC + 1], 0, 0, 0);
        }
    }
}

template<int W>
__device__ __forceinline__ void write_sq(const f4 (&acc)[9], float* sq, int lr, int lg) {
    #pragma unroll
    for (int q = 0; q < 4; ++q) {
        if (4 * lg + q == lr) {
            sq[W * 16 + lr]       = acc[0][q];       // tile (W,W)
            sq[(7 - W) * 16 + lr] = acc[8 - W][q];   // tile (7-W,7-W)
        }
    }
}

// Borjesson-Sundberg Q(z) ~ phi(z)/((1-A)z + A*sqrt(z^2+B)); rel err <~0.5%.
// q_axb = F1 + F2 - 2 F1 F2 is relative-accurate (no cancellation).
__device__ __forceinline__ float entry_ll(float g, float sqn, float sqm,
        uint_t cw, float lam, float one_m2l) {
    const float d2 = fmaxf(sqn + sqm - 2.0f * g, 0.0f);
    const float pd = __builtin_amdgcn_sqrtf(d2);
    const float A = 0.344f, B = 5.334f, IA = 0.656f, C = 0.3989422804f;
    const float z1 = 0.70710678f * pd, z2 = 0.5f * pd;
    const float e1 = __expf(-0.25f  * d2) * C;   // phi(z1)
    const float e2 = __expf(-0.125f * d2) * C;   // phi(z2)
    const float den1 = fmaf(A, __builtin_amdgcn_sqrtf(fmaf(0.5f,  d2, B)), IA * z1);
    const float den2 = fmaf(A, __builtin_amdgcn_sqrtf(fmaf(0.25f, d2, B)), IA * z2);
    const float F1 = e1 * __builtin_amdgcn_rcpf(den1);
    const float F2 = e2 * __builtin_amdgcn_rcpf(den2);
    const float qax = F1 + F2 - 2.0f * F1 * F2;
    float qp = fmaf(one_m2l, qax, lam);
    qp = fminf(fmaxf(qp, 1e-7f), 1.0f - 1e-7f);
    const float pp = 1.0f - qp;
    const float c   = bf2f((ushort_t)(cw & 0xffffu));
    const float amc = bf2f((ushort_t)(cw >> 16));
    return c * __logf(pp) + amc * __logf(qp);
}

__device__ __forceinline__ float tile_ll(f4 a, int TR, int TC, bool diag,
        int lr, int lg, const float* sq, const uint_t* __restrict__ cnt,
        float lam, float one_m2l) {
    float s = 0.0f;
    #pragma unroll
    for (int q = 0; q < 4; ++q) {
        const int n = TR * 16 + 4 * lg + q;
        const int m = TC * 16 + lr;
        if (!diag || (4 * lg + q) <= lr)
            s += entry_ll(a[q], sq[n], sq[m], cnt[n * 128 + m], lam, one_m2l);
    }
    return s;
}

template<int W>
__device__ __forceinline__ float epi(const f4 (&acc)[9], const float* sq,
        const uint_t* __restrict__ cnt, int lr, int lg, float lam, float one_m2l) {
    constexpr int RA = W, RB = 7 - W;
    float s = 0.0f;
    #pragma unroll
    for (int TC = W; TC < 8; ++TC) {
        s += tile_ll(acc[TC - W], RA, TC, (TC == RA), lr, lg, sq, cnt, lam, one_m2l);
        if (TC >= RB)
            s += tile_ll(acc[TC + 1], RB, TC, (TC == RB), lr, lg, sq, cnt, lam, one_m2l);
    }
    return s;
}

__global__ __launch_bounds__(256, 4) void ll_kernel(
        const uint_t* __restrict__ x_g,
        const float* __restrict__ l_raw, const uint_t* __restrict__ cnt,
        float* __restrict__ sums, int s_base) {
    const int li = blockIdx.x;
    const int s  = s_base + li;
    const int t  = threadIdx.x;

    __shared__ __align__(16) ushort_t Xs[NNODES * 128];   // 32 KB
    __shared__ float sq[NNODES];
    __shared__ float wsum[4];

    const uint_t* gx = x_g + (size_t)li * NNODES * 64;
    const int l = t & 63, w = t >> 6, lr = l & 15, lg = l >> 4;

    // fill LDS (swizzled) with 16B chunks; 2048 chunks over 256 threads
    #pragma unroll
    for (int ii = 0; ii < 8; ++ii) {
        const int i = t + ii * 256;
        const int row = i >> 4, j = i & 15;
        const uint4 v = *(const uint4*)(gx + row * 64 + j * 4);
        const int b = ((row << 8) + (j << 4)) ^ ((row & 7) << 4);
        *(uint4*)((char*)Xs + b) = v;
    }
    __syncthreads();

    f4 acc[9];
    #pragma unroll
    for (int i = 0; i < 9; ++i) acc[i] = (f4)(0.0f);

    switch (w) {
        case 0: gram_w<0>(Xs, acc, lr, lg); write_sq<0>(acc, sq, lr, lg); break;
        case 1: gram_w<1>(Xs, acc, lr, lg); write_sq<1>(acc, sq, lr, lg); break;
        case 2: gram_w<2>(Xs, acc, lr, lg); write_sq<2>(acc, sq, lr, lg); break;
        default: gram_w<3>(Xs, acc, lr, lg); write_sq<3>(acc, sq, lr, lg); break;
    }
    __syncthreads();

    const float lam = 0.06f * normal_cdf_f(l_raw[s]);
    const float one_m2l = 1.0f - 2.0f * lam;
    float ll = 0.0f;
    switch (w) {
        case 0: ll = epi<0>(acc, sq, cnt, lr, lg, lam, one_m2l); break;
        case 1: ll = epi<1>(acc, sq, cnt, lr, lg, lam, one_m2l); break;
        case 2: ll = epi<2>(acc, sq, cnt, lr, lg, lam, one_m2l); break;
        default: ll = epi<3>(acc, sq, cnt, lr, lg, lam, one_m2l); break;
    }

    const float wtot = wave_sum(ll);
    if (l == 0) wsum[w] = wtot;
    __syncthreads();
    if (t == 0) sums[s] = wsum[0] + wsum[1] + wsum[2] + wsum[3];
}

// ---------------------------------------------------------------------------
// Kernel 3: deterministic mean over S
// ---------------------------------------------------------------------------
__global__ __launch_bounds__(256) void reduce_kernel(
        const float* __restrict__ sums, float* __restrict__ out) {
    __shared__ double sh[256];
    const int t = threadIdx.x;
    double acc = 0.0;
    for (int i = t; i < S_TOT; i += 256) acc += (double)sums[i];
    sh[t] = acc;
    __syncthreads();
    for (int off = 128; off > 0; off >>= 1) {
        if (t < off) sh[t] += sh[t + off];
        __syncthreads();
    }
    if (t == 0) out[0] = (float)(sh[0] / (double)S_TOT);
}

// ---------------------------------------------------------------------------
extern "C" void kernel_launch(void* const* d_in, const int* in_sizes, int n_in,
                              void* d_out, int out_size, void* d_ws, size_t ws_size,
                              hipStream_t stream) {
    (void)in_sizes; (void)n_in; (void)out_size;
    const float* d_raw = (const float*)d_in[0];
    const float* c_raw = (const float*)d_in[1];
    const float* a_raw = (const float*)d_in[2];
    const float* l_raw = (const float*)d_in[3];
    const int*   all_t = (const int*)d_in[4];
    const int*   cor_t = (const int*)d_in[5];
    float* out = (float*)d_out;

    char*   ws   = (char*)d_ws;
    float*  sums = (float*)ws;                        // 8 KB
    uint_t* cnt  = (uint_t*)(ws + 8192);              // 64 KB packed counts
    char*   xbase = ws + 8192 + 65536;
    const size_t per_sample = (size_t)NNODES * 64 * sizeof(uint_t);  // 32 KB

    const size_t head = 8192 + 65536;
    size_t avail = (ws_size > head) ? ws_size - head : 0;
    int chunk = (int)(avail / per_sample);
    if (chunk > S_TOT) chunk = S_TOT;
    if (chunk < 1) chunk = 1;

    prep_counts<<<64, 256, 0, stream>>>(all_t, cor_t, cnt);

    for (int s0 = 0; s0 < S_TOT; s0 += chunk) {
        const int nblk = (S_TOT - s0 < chunk) ? (S_TOT - s0) : chunk;
        uint_t* xbuf = (uint_t*)xbase;
        traj_kernel<<<nblk, 64, 0, stream>>>(d_raw, c_raw, a_raw, xbuf, s0);
        ll_kernel<<<nblk, 256, 0, stream>>>(xbuf, l_raw, cnt, sums, s0);
    }
    reduce_kernel<<<1, 256, 0, stream>>>(sums, out);
}

// Round 12
// 100.583 us; speedup vs baseline: 1.1577x; 1.0040x over previous
//
#include <hip/hip_runtime.h>
#include <math.h>

#define S_TOT   2048
#define NNODES  128
#define D_DIM   127
#define N_STEPS 126

typedef unsigned short ushort_t;
typedef unsigned int   uint_t;
typedef __attribute__((ext_vector_type(8))) short bfrag;   // 8 bf16 = 4 VGPR
typedef __attribute__((ext_vector_type(4))) float f4;

__device__ __forceinline__ float softplus_f(float x) {
    return log1pf(expf(-fabsf(x))) + fmaxf(x, 0.0f);
}
__device__ __forceinline__ float normal_cdf_f(float x) {
    return 0.5f * (1.0f + erff(x * 0.7071067811865475f));
}
__device__ __forceinline__ float frl(float x, int lane) {
    return __int_as_float(__builtin_amdgcn_readlane(__float_as_int(x), lane));
}
// 64-lane sum via DPP; returns wave-uniform total.
__device__ __forceinline__ float wave_sum(float x) {
    float r = x; int v;
    v = __builtin_amdgcn_update_dpp(0, __float_as_int(r), 0x111, 0xf, 0xf, true); r += __int_as_float(v);
    v = __builtin_amdgcn_update_dpp(0, __float_as_int(r), 0x112, 0xf, 0xf, true); r += __int_as_float(v);
    v = __builtin_amdgcn_update_dpp(0, __float_as_int(r), 0x114, 0xf, 0xf, true); r += __int_as_float(v);
    v = __builtin_amdgcn_update_dpp(0, __float_as_int(r), 0x118, 0xf, 0xf, true); r += __int_as_float(v);
    v = __builtin_amdgcn_update_dpp(0, __float_as_int(r), 0x142, 0xa, 0xf, true); r += __int_as_float(v);
    v = __builtin_amdgcn_update_dpp(0, __float_as_int(r), 0x143, 0xc, 0xf, true); r += __int_as_float(v);
    return frl(r, 63);
}
// dual / triple interleaved reductions: independent DPP chains overlap.
__device__ __forceinline__ void wave_sum2(float a, float b, float& ra, float& rb) {
    float x = a, y = b; int v;
#define STG2(C, RM)                                                            \
    v = __builtin_amdgcn_update_dpp(0, __float_as_int(x), C, RM, 0xf, true); x += __int_as_float(v); \
    v = __builtin_amdgcn_update_dpp(0, __float_as_int(y), C, RM, 0xf, true); y += __int_as_float(v);
    STG2(0x111, 0xf) STG2(0x112, 0xf) STG2(0x114, 0xf)
    STG2(0x118, 0xf) STG2(0x142, 0xa) STG2(0x143, 0xc)
#undef STG2
    ra = frl(x, 63); rb = frl(y, 63);
}
__device__ __forceinline__ void wave_sum3(float a, float b, float c,
                                          float& ra, float& rb, float& rc) {
    float x = a, y = b, z = c; int v;
#define STG3(C, RM)                                                            \
    v = __builtin_amdgcn_update_dpp(0, __float_as_int(x), C, RM, 0xf, true); x += __int_as_float(v); \
    v = __builtin_amdgcn_update_dpp(0, __float_as_int(y), C, RM, 0xf, true); y += __int_as_float(v); \
    v = __builtin_amdgcn_update_dpp(0, __float_as_int(z), C, RM, 0xf, true); z += __int_as_float(v);
    STG3(0x111, 0xf) STG3(0x112, 0xf) STG3(0x114, 0xf)
    STG3(0x118, 0xf) STG3(0x142, 0xa) STG3(0x143, 0xc)
#undef STG3
    ra = frl(x, 63); rb = frl(y, 63); rc = frl(z, 63);
}
__device__ __forceinline__ ushort_t f2bf(float x) {        // RNE fp32 -> bf16
    uint_t u = __float_as_uint(x);
    uint_t r = u + 0x7fffu + ((u >> 16) & 1u);
    return (ushort_t)(r >> 16);
}
__device__ __forceinline__ float bf2f(ushort_t h) {
    return __uint_as_float(((uint_t)h) << 16);
}

// ---------------------------------------------------------------------------
// Kernel 0: symmetrized counts packed as bf16 pair: lo = csym, hi = asym-csym
// ---------------------------------------------------------------------------
__global__ __launch_bounds__(256) void prep_counts(
        const int* __restrict__ all_t, const int* __restrict__ cor_t,
        uint_t* __restrict__ pk) {
    int i = blockIdx.x * 256 + threadIdx.x;       // 16384
    int n = i >> 7, m = i & 127;
    int at = all_t[i], ct = cor_t[i];
    if (n != m) { at += all_t[m * 128 + n]; ct += cor_t[m * 128 + n]; }
    pk[i] = (uint_t)f2bf((float)ct) | ((uint_t)f2bf((float)(at - ct)) << 16);
}

// ---------------------------------------------------------------------------
// Kernel 1: trajectory, PAIR-FUSED. One wave per sample; lane l owns dims
// 2l, 2l+1. Two recurrence steps are fused per iteration: one dual
// wave-reduction (r0 = v.a_i, r1 = v.a_{i+1}) plus precomputed g01 = a_i.a_{i+1}
// resolves both steps' rotation scalars:
//   va_{i+1} = al0*r1 + be0*g01 ; v2 = al1*(al0 v + be0 a_i) + be1 a_{i+1}.
// Halves step count (63 pairs), reductions-on-chain, and issue per step.
// ---------------------------------------------------------------------------
#define LDR1(A, B, row)                                                       \
    { const float* _p = ap + (size_t)(row) * D_DIM + 2 * lane;                \
      A = _p[0];                                                              \
      float _t = _p[d1ok ? 1 : 0];   /* lane63 stays in-bounds */             \
      B = d1ok ? _t : 0.0f; }

#define LOAD_G(BASE, GUARD)                                                   \
    { const int _b = (BASE); const bool _gd = (GUARD);                        \
      if (!_gd || _b + 0  < 126) LDR1(sa0,  sb0,  _b + 0)  else { sa0 = 0; sb0 = 0; }   \
      if (!_gd || _b + 1  < 126) LDR1(sa1,  sb1,  _b + 1)  else { sa1 = 0; sb1 = 0; }   \
      if (!_gd || _b + 2  < 126) LDR1(sa2,  sb2,  _b + 2)  else { sa2 = 0; sb2 = 0; }   \
      if (!_gd || _b + 3  < 126) LDR1(sa3,  sb3,  _b + 3)  else { sa3 = 0; sb3 = 0; }   \
      if (!_gd || _b + 4  < 126) LDR1(sa4,  sb4,  _b + 4)  else { sa4 = 0; sb4 = 0; }   \
      if (!_gd || _b + 5  < 126) LDR1(sa5,  sb5,  _b + 5)  else { sa5 = 0; sb5 = 0; }   \
      if (!_gd || _b + 6  < 126) LDR1(sa6,  sb6,  _b + 6)  else { sa6 = 0; sb6 = 0; }   \
      if (!_gd || _b + 7  < 126) LDR1(sa7,  sb7,  _b + 7)  else { sa7 = 0; sb7 = 0; }   \
      if (!_gd || _b + 8  < 126) LDR1(sa8,  sb8,  _b + 8)  else { sa8 = 0; sb8 = 0; }   \
      if (!_gd || _b + 9  < 126) LDR1(sa9,  sb9,  _b + 9)  else { sa9 = 0; sb9 = 0; }   \
      if (!_gd || _b + 10 < 126) LDR1(sa10, sb10, _b + 10) else { sa10 = 0; sb10 = 0; } \
      if (!_gd || _b + 11 < 126) LDR1(sa11, sb11, _b + 11) else { sa11 = 0; sb11 = 0; } \
      if (!_gd || _b + 12 < 126) LDR1(sa12, sb12, _b + 12) else { sa12 = 0; sb12 = 0; } \
      if (!_gd || _b + 13 < 126) LDR1(sa13, sb13, _b + 13) else { sa13 = 0; sb13 = 0; } \
      if (!_gd || _b + 14 < 126) LDR1(sa14, sb14, _b + 14) else { sa14 = 0; sb14 = 0; } \
      if (!_gd || _b + 15 < 126) LDR1(sa15, sb15, _b + 15) else { sa15 = 0; sb15 = 0; } }

#define WRITE_G(SB)                                                           \
    { const int _s = (SB);                                                    \
      *(float2*)&abuf[_s + 0 ][2 * lane] = make_float2(sa0,  sb0);            \
      *(float2*)&abuf[_s + 1 ][2 * lane] = make_float2(sa1,  sb1);            \
      *(float2*)&abuf[_s + 2 ][2 * lane] = make_float2(sa2,  sb2);            \
      *(float2*)&abuf[_s + 3 ][2 * lane] = make_float2(sa3,  sb3);            \
      *(float2*)&abuf[_s + 4 ][2 * lane] = make_float2(sa4,  sb4);            \
      *(float2*)&abuf[_s + 5 ][2 * lane] = make_float2(sa5,  sb5);            \
      *(float2*)&abuf[_s + 6 ][2 * lane] = make_float2(sa6,  sb6);            \
      *(float2*)&abuf[_s + 7 ][2 * lane] = make_float2(sa7,  sb7);            \
      *(float2*)&abuf[_s + 8 ][2 * lane] = make_float2(sa8,  sb8);            \
      *(float2*)&abuf[_s + 9 ][2 * lane] = make_float2(sa9,  sb9);            \
      *(float2*)&abuf[_s + 10][2 * lane] = make_float2(sa10, sb10);           \
      *(float2*)&abuf[_s + 11][2 * lane] = make_float2(sa11, sb11);           \
      *(float2*)&abuf[_s + 12][2 * lane] = make_float2(sa12, sb12);           \
      *(float2*)&abuf[_s + 13][2 * lane] = make_float2(sa13, sb13);           \
      *(float2*)&abuf[_s + 14][2 * lane] = make_float2(sa14, sb14);           \
      *(float2*)&abuf[_s + 15][2 * lane] = make_float2(sa15, sb15); }

#define RD_RING(SL, ROW)                                                      \
    { float2 t = *(float2*)&abuf[(ROW) & 31][2 * lane];                       \
      raR[SL] = t.x; rbR[SL] = t.y; }

// Fused pair. S0,S1: slots rows i,i+1. S4,S5: rows i+4,i+5 (next-N precompute).
// S6,S7: refill slots. S2,S3 double as xstage slots for rows i+2,i+3.
#define PAIR_CORE(S0, S1, S2, S3, S4, S5, S6, S7, R6, R7, TI0, TI1, TD0, TD1, \
                  FLUSH, FROW)                                                \
    {                                                                         \
        /* ---- on-chain: dual reduction + fused scalar tail ---- */          \
        float m0 = fmaf(v0, raR[S0], v1 * rbR[S0]);                           \
        float m1 = fmaf(v0, raR[S1], v1 * rbR[S1]);                           \
        float r0, r1; wave_sum2(m0, m1, r0, r1);                              \
        const float va0 = r0;                                                 \
        float ua0 = fmaf(fmaf(-V0, aE00, va0), rcp_v, aE00);                  \
        float w10 = fmaf(-ua0, V1s, aE01);                                    \
        float iv0 = __builtin_amdgcn_rsqf(fmaf(-va0, va0, aaU0));             \
        float sf0 = s0u * ((w10 >= 0.0f) ? -iv0 : iv0);                       \
        float al0 = fmaf(-sf0, va0, c0u), be0 = sf0;                          \
        float V0a = fmaf(al0, V0, be0 * aE00);                                \
        float V1a = fmaf(al0, V1, be0 * aE01);                                \
        float sg1 = copysignf(1.0f, V0a);                                     \
        float rv1 = __builtin_amdgcn_rcpf(V0a + sg1);                         \
        float V1as = V1a * sg1;                                               \
        float va1 = fmaf(al0, r1, be0 * gU);                                  \
        float ua1 = fmaf(fmaf(-V0a, aE10, va1), rv1, aE10);                   \
        float w11 = fmaf(-ua1, V1as, aE11);                                   \
        float iv1 = __builtin_amdgcn_rsqf(fmaf(-va1, va1, aaU1));             \
        float sf1 = s1u * ((w11 >= 0.0f) ? -iv1 : iv1);                       \
        float al1 = fmaf(-sf1, va1, c1u), be1 = sf1;                          \
        V0 = fmaf(al1, V0a, be1 * aE10);                                      \
        V1 = fmaf(al1, V1a, be1 * aE11);                                      \
        { float sg = copysignf(1.0f, V0);                                     \
          rcp_v = __builtin_amdgcn_rcpf(V0 + sg); V1s = V1 * sg; }            \
        /* ---- per-lane v, x ---- */                                         \
        float w0a = fmaf(al0, v0, be0 * raR[S0]);                             \
        float w1a = fmaf(al0, v1, be0 * rbR[S0]);                             \
        v0 = fmaf(al1, w0a, be1 * raR[S1]);                                   \
        v1 = fmaf(al1, w1a, be1 * rbR[S1]);                                   \
        x0 = fmaf(d0u, w0a, x0); x1 = fmaf(d0u, w1a, x1);                     \
        { uint_t pk;                                                          \
          asm("v_cvt_pk_bf16_f32 %0, %1, %2" : "=v"(pk) : "v"(x0), "v"(x1));  \
          xstage[(S2) * 64 + lane] = pk; }                                    \
        x0 = fmaf(d1u, v0, x0); x1 = fmaf(d1u, v1, x1);                       \
        { uint_t pk;                                                          \
          asm("v_cvt_pk_bf16_f32 %0, %1, %2" : "=v"(pk) : "v"(x0), "v"(x1));  \
          xstage[(S3) * 64 + lane] = pk; }                                    \
        /* ---- shift N -> U ---- */                                          \
        aaU0 = aaN0; aaU1 = aaN1; gU = gN;                                    \
        aE00 = aE00N; aE01 = aE01N; aE10 = aE10N; aE11 = aE11N;               \
        c0u = c0N; s0u = s0N; c1u = c1N; s1u = s1N; d0u = d0N; d1u = d1N;     \
        /* ---- off-chain: precompute N for pair p+2 (rows i+4,i+5) ---- */   \
        { float p0 = fmaf(raR[S4], raR[S4], rbR[S4] * rbR[S4]);               \
          float p1 = fmaf(raR[S5], raR[S5], rbR[S5] * rbR[S5]);               \
          float p2 = fmaf(raR[S4], raR[S5], rbR[S4] * rbR[S5]);               \
          wave_sum3(p0, p1, p2, aaN0, aaN1, gN); }                            \
        aE00N = frl(raR[S4], 0); aE01N = frl(rbR[S4], 0);                     \
        aE10N = frl(raR[S5], 0); aE11N = frl(rbR[S5], 0);                     \
        { float2 cs = cls2[TI0]; c0N = cs.x; s0N = cs.y; }                    \
        { float2 cs = cls2[TI1]; c1N = cs.x; s1N = cs.y; }                    \
        d0N = dls[TD0]; d1N = dls[TD1];                                       \
        RD_RING(S6, R6)                                                       \
        RD_RING(S7, R7)                                                       \
        if (FLUSH) {                                                          \
            uint4 t0 = *(uint4*)&xstage[4 * lane];                            \
            uint4 t1 = *(uint4*)&xstage[256 + 4 * lane];                      \
            uint_t* dst = xg + (FROW) * 64;                                   \
            *(uint4*)(dst + 4 * lane) = t0;                                   \
            *(uint4*)(dst + 256 + 4 * lane) = t1;                             \
        }                                                                     \
    }

// main-loop pair J (0..7), step base ibp = 16*g
#define MPAIR(J) PAIR_CORE((2*(J)) & 7, (2*(J)+1) & 7, (2*(J)+2) & 7,         \
                           (2*(J)+3) & 7, (2*(J)+4) & 7, (2*(J)+5) & 7,       \
                           (2*(J)+6) & 7, (2*(J)+7) & 7,                      \
                           ibp + 2*(J) + 6, ibp + 2*(J) + 7,                  \
                           ibp + 2*(J) + 4, ibp + 2*(J) + 5,                  \
                           ibp + 2*(J) + 5, ibp + 2*(J) + 6,                  \
                           ((J) == 2 || (J) == 6), ibp + 2*(J) - 4)
// tail pair J (0..6), step base 112 (pairs 56..62); clamp lookaheads
#define TCL(V, M) (((V) < (M)) ? (V) : (M))
#define TPAIR(J) PAIR_CORE((2*(J)) & 7, (2*(J)+1) & 7, (2*(J)+2) & 7,         \
                           (2*(J)+3) & 7, (2*(J)+4) & 7, (2*(J)+5) & 7,       \
                           (2*(J)+6) & 7, (2*(J)+7) & 7,                      \
                           TCL(112 + 2*(J) + 6, 125), TCL(112 + 2*(J) + 7, 125), \
                           TCL(112 + 2*(J) + 4, 127), TCL(112 + 2*(J) + 5, 127), \
                           TCL(112 + 2*(J) + 5, 127), TCL(112 + 2*(J) + 6, 127), \
                           ((J) == 2 || (J) == 6), 112 + 2*(J) - 4)

__global__
__attribute__((amdgpu_flat_work_group_size(64, 64), amdgpu_waves_per_eu(2, 2)))
void traj_kernel(
        const float* __restrict__ d_raw, const float* __restrict__ c_raw,
        const float* __restrict__ a_raw,
        uint_t* __restrict__ xout, int s_base) {
    const int li = blockIdx.x;
    const int s  = s_base + li;
    const int lane = threadIdx.x;
    const bool d1ok = lane < 63;                  // dim 2l+1 <= 126

    __shared__ __align__(16) float abuf[32][128]; // 16 KB (2 groups x 16 rows)
    __shared__ __align__(16) uint_t xstage[512];  // 2 KB (8 x-rows)
    __shared__ float  dls[128];
    __shared__ float2 cls2[128];

    // d (softplus'd), cos/sin tables for uniform broadcast reads (padded 0)
    float t0 = softplus_f(d_raw[(size_t)s * D_DIM + lane]);
    dls[lane] = t0;
    dls[64 + lane] = d1ok ? softplus_f(d_raw[(size_t)s * D_DIM + 64 + lane]) : 0.0f;
    {
        float cv = c_raw[(size_t)s * N_STEPS + lane];
        cls2[lane] = make_float2(__cosf(cv), __sinf(cv));
        if (lane < 62) {
            float cv2 = c_raw[(size_t)s * N_STEPS + 64 + lane];
            cls2[64 + lane] = make_float2(__cosf(cv2), __sinf(cv2));
        } else {
            cls2[64 + lane] = make_float2(0.0f, 0.0f);
        }
    }

    const float* ap = a_raw + (size_t)s * N_STEPS * D_DIM;
    uint_t* xg = xout + (size_t)li * NNODES * 64;

    // staging regs: one 16-row group
    float sa0, sa1, sa2, sa3, sa4, sa5, sa6, sa7,
          sa8, sa9, sa10, sa11, sa12, sa13, sa14, sa15;
    float sb0, sb1, sb2, sb3, sb4, sb5, sb6, sb7,
          sb8, sb9, sb10, sb11, sb12, sb13, sb14, sb15;

    // prologue: G0,G1 staged+written; G2 loaded (written at boundary g=0)
    LOAD_G(0, false)  WRITE_G(0)
    LOAD_G(16, false) WRITE_G(16)
    LOAD_G(32, false)

    // 8-slot register ring primed with rows 0..5
    float raR[8], rbR[8];
    RD_RING(0, 0) RD_RING(1, 1) RD_RING(2, 2)
    RD_RING(3, 3) RD_RING(4, 4) RD_RING(5, 5)
    raR[6] = 0.0f; rbR[6] = 0.0f; raR[7] = 0.0f; rbR[7] = 0.0f;

    // U = pair 0 (rows 0,1), N = pair 1 (rows 2,3)
    float aaU0, aaU1, gU, aaN0, aaN1, gN;
    {
        float p0 = fmaf(raR[0], raR[0], rbR[0] * rbR[0]);
        float p1 = fmaf(raR[1], raR[1], rbR[1] * rbR[1]);
        float p2 = fmaf(raR[0], raR[1], rbR[0] * rbR[1]);
        wave_sum3(p0, p1, p2, aaU0, aaU1, gU);
    }
    {
        float p0 = fmaf(raR[2], raR[2], rbR[2] * rbR[2]);
        float p1 = fmaf(raR[3], raR[3], rbR[3] * rbR[3]);
        float p2 = fmaf(raR[2], raR[3], rbR[2] * rbR[3]);
        wave_sum3(p0, p1, p2, aaN0, aaN1, gN);
    }
    float aE00 = frl(raR[0], 0), aE01 = frl(rbR[0], 0);
    float aE10 = frl(raR[1], 0), aE11 = frl(rbR[1], 0);
    float aE00N = frl(raR[2], 0), aE01N = frl(rbR[2], 0);
    float aE10N = frl(raR[3], 0), aE11N = frl(rbR[3], 0);
    float c0u, s0u, c1u, s1u, c0N, s0N, c1N, s1N;
    { float2 cs = cls2[0]; c0u = cs.x; s0u = cs.y; }
    { float2 cs = cls2[1]; c1u = cs.x; s1u = cs.y; }
    { float2 cs = cls2[2]; c0N = cs.x; s0N = cs.y; }
    { float2 cs = cls2[3]; c1N = cs.x; s1N = cs.y; }
    float d0u = dls[1], d1u = dls[2], d0N = dls[3], d1N = dls[4];

    // state
    float v0 = (lane == 0) ? 1.0f : 0.0f, v1 = 0.0f;
    float V0 = 1.0f, V1 = 0.0f, V1s = 0.0f, rcp_v = 0.5f;
    float x0 = (lane == 0) ? t0 : 0.0f, x1 = 0.0f;

    // x rows 0,1 into staging slots 0,1
    xstage[lane] = 0u;
    {
        uint_t pk0;
        asm("v_cvt_pk_bf16_f32 %0, %1, %2" : "=v"(pk0) : "v"(x0), "v"(x1));
        xstage[64 + lane] = pk0;
    }

    // main: 7 groups x 8 pairs (steps 0..111)
    #pragma unroll 1
    for (int g = 0; g < 7; ++g) {
        const int ibp = g << 4;
        MPAIR(0) MPAIR(1) MPAIR(2) MPAIR(3)
        MPAIR(4) MPAIR(5) MPAIR(6) MPAIR(7)
        if (g <= 5) { WRITE_G((g & 1) << 4) }     // write G_{g+2}
        if (g <= 4) LOAD_G((g + 3) << 4, g == 4)  // load  G_{g+3}
    }
    // tail: pairs 56..62 (steps 112..125); flushes at J=2 (rows 112..119)
    // and J=6 (rows 120..127)
    TPAIR(0) TPAIR(1) TPAIR(2) TPAIR(3)
    TPAIR(4) TPAIR(5) TPAIR(6)
}
#undef MPAIR
#undef TPAIR
#undef TCL
#undef PAIR_CORE
#undef RD_RING
#undef LOAD_G
#undef WRITE_G
#undef LDR1

// ---------------------------------------------------------------------------
// Kernel 2: MFMA gram (single 32KB bf16 LDS stage) + B-S tail log-lik.
// 4 waves; wave w owns tile-rows {w, 7-w} via template<int W> (acc = 9 f4).
// ---------------------------------------------------------------------------
__device__ __forceinline__ bfrag ldfrag(const ushort_t* base, int row, int kelem) {
    int byte = ((row << 8) + (kelem << 1)) ^ ((row & 7) << 4);
    return *(const bfrag*)((const char*)base + byte);
}

template<int W>
__device__ __forceinline__ void gram_w(const ushort_t* Xs, f4 (&acc)[9],
                                       int lr, int lg) {
    constexpr int RA = W, RB = 7 - W;
    #pragma unroll
    for (int ks = 0; ks < 4; ++ks) {
        const int kb = ks * 32 + lg * 8;
        const bfrag ha = ldfrag(Xs, RA * 16 + lr, kb);
        const bfrag hb = ldfrag(Xs, RB * 16 + lr, kb);
        #pragma unroll
        for (int TC = W; TC < 8; ++TC) {
            const bfrag bh = ldfrag(Xs, TC * 16 + lr, kb);
            acc[TC - W] = __builtin_amdgcn_mfma_f32_16x16x32_bf16(ha, bh, acc[TC - W], 0, 0, 0);
            if (TC >= RB)
                acc[TC + 1] = __builtin_amdgcn_mfma_f32_16x16x32_bf16(hb, bh, acc[TC + 1], 0, 0, 0);
        }
    }
}

template<int W>
__device__ __forceinline__ void write_sq(const f4 (&acc)[9], float* sq, int lr, int lg) {
    #pragma unroll
    for (int q = 0; q < 4; ++q) {
        if (4 * lg + q == lr) {
            sq[W * 16 + lr]       = acc[0][q];       // tile (W,W)
            sq[(7 - W) * 16 + lr] = acc[8 - W][q];   // tile (7-W,7-W)
        }
    }
}

// Borjesson-Sundberg Q(z) ~ phi(z)/((1-A)z + A*sqrt(z^2+B)); rel err <~0.5%.
// q_axb = F1 + F2 - 2 F1 F2 is relative-accurate (no cancellation).
__device__ __forceinline__ float entry_ll(float g, float sqn, float sqm,
        uint_t cw, float lam, float one_m2l) {
    const float d2 = fmaxf(sqn + sqm - 2.0f * g, 0.0f);
    const float pd = __builtin_amdgcn_sqrtf(d2);
    const float A = 0.344f, B = 5.334f, IA = 0.656f, C = 0.3989422804f;
    const float z1 = 0.70710678f * pd, z2 = 0.5f * pd;
    const float e1 = __expf(-0.25f  * d2) * C;   // phi(z1)
    const float e2 = __expf(-0.125f * d2) * C;   // phi(z2)
    const float den1 = fmaf(A, __builtin_amdgcn_sqrtf(fmaf(0.5f,  d2, B)), IA * z1);
    const float den2 = fmaf(A, __builtin_amdgcn_sqrtf(fmaf(0.25f, d2, B)), IA * z2);
    const float F1 = e1 * __builtin_amdgcn_rcpf(den1);
    const float F2 = e2 * __builtin_amdgcn_rcpf(den2);
    const float qax = F1 + F2 - 2.0f * F1 * F2;
    float qp = fmaf(one_m2l, qax, lam);
    qp = fminf(fmaxf(qp, 1e-7f), 1.0f - 1e-7f);
    const float pp = 1.0f - qp;
    const float c   = bf2f((ushort_t)(cw & 0xffffu));
    const float amc = bf2f((ushort_t)(cw >> 16));
    return c * __logf(pp) + amc * __logf(qp);
}

__device__ __forceinline__ float tile_ll(f4 a, int TR, int TC, bool diag,
        int lr, int lg, const float* sq, const uint_t* __restrict__ cnt,
        float lam, float one_m2l) {
    float s = 0.0f;
    #pragma unroll
    for (int q = 0; q < 4; ++q) {
        const int n = TR * 16 + 4 * lg + q;
        const int m = TC * 16 + lr;
        if (!diag || (4 * lg + q) <= lr)
            s += entry_ll(a[q], sq[n], sq[m], cnt[n * 128 + m], lam, one_m2l);
    }
    return s;
}

template<int W>
__device__ __forceinline__ float epi(const f4 (&acc)[9], const float* sq,
        const uint_t* __restrict__ cnt, int lr, int lg, float lam, float one_m2l) {
    constexpr int RA = W, RB = 7 - W;
    float s = 0.0f;
    #pragma unroll
    for (int TC = W; TC < 8; ++TC) {
        s += tile_ll(acc[TC - W], RA, TC, (TC == RA), lr, lg, sq, cnt, lam, one_m2l);
        if (TC >= RB)
            s += tile_ll(acc[TC + 1], RB, TC, (TC == RB), lr, lg, sq, cnt, lam, one_m2l);
    }
    return s;
}

__global__ __launch_bounds__(256, 4) void ll_kernel(
        const uint_t* __restrict__ x_g,
        const float* __restrict__ l_raw, const uint_t* __restrict__ cnt,
        float* __restrict__ sums, int s_base) {
    const int li = blockIdx.x;
    const int s  = s_base + li;
    const int t  = threadIdx.x;

    __shared__ __align__(16) ushort_t Xs[NNODES * 128];   // 32 KB
    __shared__ float sq[NNODES];
    __shared__ float wsum[4];

    const uint_t* gx = x_g + (size_t)li * NNODES * 64;
    const int l = t & 63, w = t >> 6, lr = l & 15, lg = l >> 4;

    // fill LDS (swizzled) with 16B chunks; 2048 chunks over 256 threads
    #pragma unroll
    for (int ii = 0; ii < 8; ++ii) {
        const int i = t + ii * 256;
        const int row = i >> 4, j = i & 15;
        const uint4 v = *(const uint4*)(gx + row * 64 + j * 4);
        const int b = ((row << 8) + (j << 4)) ^ ((row & 7) << 4);
        *(uint4*)((char*)Xs + b) = v;
    }
    __syncthreads();

    f4 acc[9];
    #pragma unroll
    for (int i = 0; i < 9; ++i) acc[i] = (f4)(0.0f);

    switch (w) {
        case 0: gram_w<0>(Xs, acc, lr, lg); write_sq<0>(acc, sq, lr, lg); break;
        case 1: gram_w<1>(Xs, acc, lr, lg); write_sq<1>(acc, sq, lr, lg); break;
        case 2: gram_w<2>(Xs, acc, lr, lg); write_sq<2>(acc, sq, lr, lg); break;
        default: gram_w<3>(Xs, acc, lr, lg); write_sq<3>(acc, sq, lr, lg); break;
    }
    __syncthreads();

    const float lam = 0.06f * normal_cdf_f(l_raw[s]);
    const float one_m2l = 1.0f - 2.0f * lam;
    float ll = 0.0f;
    switch (w) {
        case 0: ll = epi<0>(acc, sq, cnt, lr, lg, lam, one_m2l); break;
        case 1: ll = epi<1>(acc, sq, cnt, lr, lg, lam, one_m2l); break;
        case 2: ll = epi<2>(acc, sq, cnt, lr, lg, lam, one_m2l); break;
        default: ll = epi<3>(acc, sq, cnt, lr, lg, lam, one_m2l); break;
    }

    const float wtot = wave_sum(ll);
    if (l == 0) wsum[w] = wtot;
    __syncthreads();
    if (t == 0) sums[s] = wsum[0] + wsum[1] + wsum[2] + wsum[3];
}

// ---------------------------------------------------------------------------
// Kernel 3: deterministic mean over S
// ---------------------------------------------------------------------------
__global__ __launch_bounds__(256) void reduce_kernel(
        const float* __restrict__ sums, float* __restrict__ out) {
    __shared__ double sh[256];
    const int t = threadIdx.x;
    double acc = 0.0;
    for (int i = t; i < S_TOT; i += 256) acc += (double)sums[i];
    sh[t] = acc;
    __syncthreads();
    for (int off = 128; off > 0; off >>= 1) {
        if (t < off) sh[t] += sh[t + off];
        __syncthreads();
    }
    if (t == 0) out[0] = (float)(sh[0] / (double)S_TOT);
}

// ---------------------------------------------------------------------------
extern "C" void kernel_launch(void* const* d_in, const int* in_sizes, int n_in,
                              void* d_out, int out_size, void* d_ws, size_t ws_size,
                              hipStream_t stream) {
    (void)in_sizes; (void)n_in; (void)out_size;
    const float* d_raw = (const float*)d_in[0];
    const float* c_raw = (const float*)d_in[1];
    const float* a_raw = (const float*)d_in[2];
    const float* l_raw = (const float*)d_in[3];
    const int*   all_t = (const int*)d_in[4];
    const int*   cor_t = (const int*)d_in[5];
    float* out = (float*)d_out;

    char*   ws   = (char*)d_ws;
    float*  sums = (float*)ws;                        // 8 KB
    uint_t* cnt  = (uint_t*)(ws + 8192);              // 64 KB packed counts
    char*   xbase = ws + 8192 + 65536;
    const size_t per_sample = (size_t)NNODES * 64 * sizeof(uint_t);  // 32 KB

    const size_t head = 8192 + 65536;
    size_t avail = (ws_size > head) ? ws_size - head : 0;
    int chunk = (int)(avail / per_sample);
    if (chunk > S_TOT) chunk = S_TOT;
    if (chunk < 1) chunk = 1;

    prep_counts<<<64, 256, 0, stream>>>(all_t, cor_t, cnt);

    for (int s0 = 0; s0 < S_TOT; s0 += chunk) {
        const int nblk = (S_TOT - s0 < chunk) ? (S_TOT - s0) : chunk;
        uint_t* xbuf = (uint_t*)xbase;
        traj_kernel<<<nblk, 64, 0, stream>>>(d_raw, c_raw, a_raw, xbuf, s0);
        ll_kernel<<<nblk, 256, 0, stream>>>(xbuf, l_raw, cnt, sums, s0);
    }
    reduce_kernel<<<1, 256, 0, stream>>>(sums, out);
}

// Round 13
// 100.064 us; speedup vs baseline: 1.1637x; 1.0052x over previous
//
#include <hip/hip_runtime.h>
#include <math.h>

#define S_TOT   2048
#define NNODES  128
#define D_DIM   127
#define N_STEPS 126

typedef unsigned short ushort_t;
typedef unsigned int   uint_t;
typedef __attribute__((ext_vector_type(8))) short bfrag;   // 8 bf16 = 4 VGPR
typedef __attribute__((ext_vector_type(4))) float f4;

__device__ __forceinline__ float softplus_f(float x) {
    return log1pf(expf(-fabsf(x))) + fmaxf(x, 0.0f);
}
__device__ __forceinline__ float normal_cdf_f(float x) {
    return 0.5f * (1.0f + erff(x * 0.7071067811865475f));
}
__device__ __forceinline__ float frl(float x, int lane) {
    return __int_as_float(__builtin_amdgcn_readlane(__float_as_int(x), lane));
}
// 64-lane sum via DPP; returns wave-uniform total.
__device__ __forceinline__ float wave_sum(float x) {
    float r = x; int v;
    v = __builtin_amdgcn_update_dpp(0, __float_as_int(r), 0x111, 0xf, 0xf, true); r += __int_as_float(v);
    v = __builtin_amdgcn_update_dpp(0, __float_as_int(r), 0x112, 0xf, 0xf, true); r += __int_as_float(v);
    v = __builtin_amdgcn_update_dpp(0, __float_as_int(r), 0x114, 0xf, 0xf, true); r += __int_as_float(v);
    v = __builtin_amdgcn_update_dpp(0, __float_as_int(r), 0x118, 0xf, 0xf, true); r += __int_as_float(v);
    v = __builtin_amdgcn_update_dpp(0, __float_as_int(r), 0x142, 0xa, 0xf, true); r += __int_as_float(v);
    v = __builtin_amdgcn_update_dpp(0, __float_as_int(r), 0x143, 0xc, 0xf, true); r += __int_as_float(v);
    return frl(r, 63);
}
__device__ __forceinline__ ushort_t f2bf(float x) {        // RNE fp32 -> bf16
    uint_t u = __float_as_uint(x);
    uint_t r = u + 0x7fffu + ((u >> 16) & 1u);
    return (ushort_t)(r >> 16);
}
__device__ __forceinline__ float bf2f(ushort_t h) {
    return __uint_as_float(((uint_t)h) << 16);
}

// ---------------------------------------------------------------------------
// Kernel 0: symmetrized counts packed as bf16 pair: lo = csym, hi = asym-csym
// ---------------------------------------------------------------------------
__global__ __launch_bounds__(256) void prep_counts(
        const int* __restrict__ all_t, const int* __restrict__ cor_t,
        uint_t* __restrict__ pk) {
    int i = blockIdx.x * 256 + threadIdx.x;       // 16384
    int n = i >> 7, m = i & 127;
    int at = all_t[i], ct = cor_t[i];
    if (n != m) { at += all_t[m * 128 + n]; ct += cor_t[m * 128 + n]; }
    pk[i] = (uint_t)f2bf((float)ct) | ((uint_t)f2bf((float)(at - ct)) << 16);
}

// ---------------------------------------------------------------------------
// Kernel 1: trajectory. Identical math/schedule to round 11 (absmax 0.0),
// but the hot loop is ROLLED into 4-step bodies (ring slots compile-time via
// mod-4 alignment; step index / table indices / flush runtime-uniform).
// Hot-loop code size drops ~4x (16-step unroll ~14KB -> ~4KB) to fit I$.
// ---------------------------------------------------------------------------
#define LDR1(A, B, row)                                                       \
    { const float* _p = ap + (size_t)(row) * D_DIM + 2 * lane;                \
      A = _p[0];                                                              \
      float _t = _p[d1ok ? 1 : 0];   /* lane63 stays in-bounds */             \
      B = d1ok ? _t : 0.0f; }

#define LOAD_G(BASE, GUARD)                                                   \
    { const int _b = (BASE); const bool _gd = (GUARD);                        \
      if (!_gd || _b + 0  < 126) LDR1(sa0,  sb0,  _b + 0)  else { sa0 = 0; sb0 = 0; }   \
      if (!_gd || _b + 1  < 126) LDR1(sa1,  sb1,  _b + 1)  else { sa1 = 0; sb1 = 0; }   \
      if (!_gd || _b + 2  < 126) LDR1(sa2,  sb2,  _b + 2)  else { sa2 = 0; sb2 = 0; }   \
      if (!_gd || _b + 3  < 126) LDR1(sa3,  sb3,  _b + 3)  else { sa3 = 0; sb3 = 0; }   \
      if (!_gd || _b + 4  < 126) LDR1(sa4,  sb4,  _b + 4)  else { sa4 = 0; sb4 = 0; }   \
      if (!_gd || _b + 5  < 126) LDR1(sa5,  sb5,  _b + 5)  else { sa5 = 0; sb5 = 0; }   \
      if (!_gd || _b + 6  < 126) LDR1(sa6,  sb6,  _b + 6)  else { sa6 = 0; sb6 = 0; }   \
      if (!_gd || _b + 7  < 126) LDR1(sa7,  sb7,  _b + 7)  else { sa7 = 0; sb7 = 0; }   \
      if (!_gd || _b + 8  < 126) LDR1(sa8,  sb8,  _b + 8)  else { sa8 = 0; sb8 = 0; }   \
      if (!_gd || _b + 9  < 126) LDR1(sa9,  sb9,  _b + 9)  else { sa9 = 0; sb9 = 0; }   \
      if (!_gd || _b + 10 < 126) LDR1(sa10, sb10, _b + 10) else { sa10 = 0; sb10 = 0; } \
      if (!_gd || _b + 11 < 126) LDR1(sa11, sb11, _b + 11) else { sa11 = 0; sb11 = 0; } \
      if (!_gd || _b + 12 < 126) LDR1(sa12, sb12, _b + 12) else { sa12 = 0; sb12 = 0; } \
      if (!_gd || _b + 13 < 126) LDR1(sa13, sb13, _b + 13) else { sa13 = 0; sb13 = 0; } \
      if (!_gd || _b + 14 < 126) LDR1(sa14, sb14, _b + 14) else { sa14 = 0; sb14 = 0; } \
      if (!_gd || _b + 15 < 126) LDR1(sa15, sb15, _b + 15) else { sa15 = 0; sb15 = 0; } }

#define WRITE_G(SB)                                                           \
    { const int _s = (SB);                                                    \
      *(float2*)&abuf[_s + 0 ][2 * lane] = make_float2(sa0,  sb0);            \
      *(float2*)&abuf[_s + 1 ][2 * lane] = make_float2(sa1,  sb1);            \
      *(float2*)&abuf[_s + 2 ][2 * lane] = make_float2(sa2,  sb2);            \
      *(float2*)&abuf[_s + 3 ][2 * lane] = make_float2(sa3,  sb3);            \
      *(float2*)&abuf[_s + 4 ][2 * lane] = make_float2(sa4,  sb4);            \
      *(float2*)&abuf[_s + 5 ][2 * lane] = make_float2(sa5,  sb5);            \
      *(float2*)&abuf[_s + 6 ][2 * lane] = make_float2(sa6,  sb6);            \
      *(float2*)&abuf[_s + 7 ][2 * lane] = make_float2(sa7,  sb7);            \
      *(float2*)&abuf[_s + 8 ][2 * lane] = make_float2(sa8,  sb8);            \
      *(float2*)&abuf[_s + 9 ][2 * lane] = make_float2(sa9,  sb9);            \
      *(float2*)&abuf[_s + 10][2 * lane] = make_float2(sa10, sb10);           \
      *(float2*)&abuf[_s + 11][2 * lane] = make_float2(sa11, sb11);           \
      *(float2*)&abuf[_s + 12][2 * lane] = make_float2(sa12, sb12);           \
      *(float2*)&abuf[_s + 13][2 * lane] = make_float2(sa13, sb13);           \
      *(float2*)&abuf[_s + 14][2 * lane] = make_float2(sa14, sb14);           \
      *(float2*)&abuf[_s + 15][2 * lane] = make_float2(sa15, sb15); }

// I: step index (runtime, wave-uniform); SC/SA/SR: compile-time ring slots;
// ROWRD: abuf refill row (pre-masked); CLSI/DLSI: lookahead indices;
// FLUSH: runtime-uniform bool; flush writes rows (I-5)..(I+2).
#define STEP_CORE(I, SC, SA, SR, ROWRD, CLSI, DLSI, FLUSH)                    \
    {                                                                         \
        const float ca = ra_r[SC], cb = rb_r[SC];                             \
        float va = wave_sum(fmaf(v0, ca, v1 * cb));                           \
        float ua = fmaf(fmaf(-vp0, aE0U, va), rcp_v, aE0U);                   \
        float w1 = fmaf(-ua, vp1s, aE1U);                                     \
        float inv = __builtin_amdgcn_rsqf(fmaf(-va, va, aaU));                \
        float invs = (w1 >= 0.0f) ? -inv : inv;                               \
        float sf = sU * invs;                                                 \
        float nv0 = fmaf(cU, v0, sf * fmaf(-va, v0, ca));                     \
        float nv1 = fmaf(cU, v1, sf * fmaf(-va, v1, cb));                     \
        float np0 = fmaf(cU, vp0, sf * fmaf(-va, vp0, aE0U));                 \
        float np1 = fmaf(cU, vp1, sf * fmaf(-va, vp1, aE1U));                 \
        v0 = nv0; v1 = nv1; vp0 = np0; vp1 = np1;                             \
        { float ns = copysignf(1.0f, vp0);                                    \
          rcp_v = __builtin_amdgcn_rcpf(vp0 + ns); vp1s = vp1 * ns; }         \
        x0 = fmaf(dU, v0, x0); x1 = fmaf(dU, v1, x1);                         \
        { uint_t pk;                                                          \
          asm("v_cvt_pk_bf16_f32 %0, %1, %2" : "=v"(pk) : "v"(x0), "v"(x1));  \
          xstage[(((I) + 2) & 7) * 64 + lane] = pk; }                         \
        aaU = aa1; aE0U = aE0_1; aE1U = aE1_1; cU = c1; sU = s1; dU = d1;     \
        aa1 = wave_sum(fmaf(ra_r[SA], ra_r[SA], rb_r[SA] * rb_r[SA]));        \
        aE0_1 = frl(ra_r[SA], 0); aE1_1 = frl(rb_r[SA], 0);                   \
        { float2 cs = cls2[CLSI]; c1 = cs.x; s1 = cs.y; }                     \
        d1 = dls[DLSI];                                                       \
        { float2 nx = *(float2*)&abuf[ROWRD][2 * lane];                       \
          ra_r[SR] = nx.x; rb_r[SR] = nx.y; }                                 \
        if (FLUSH) {   /* rows (I-5)..(I+2); slots linear since I%8==5 */     \
            uint4 t0 = *(uint4*)&xstage[4 * lane];                            \
            uint4 t1 = *(uint4*)&xstage[256 + 4 * lane];                      \
            uint_t* dst = xg + ((I) - 5) * 64;                                \
            *(uint4*)(dst + 4 * lane) = t0;                                   \
            *(uint4*)(dst + 256 + 4 * lane) = t1;                             \
        }                                                                     \
    }

#define RR(v) ((((v) < 125) ? (v) : 125) & 31)     // clamped refill row

__global__
__attribute__((amdgpu_flat_work_group_size(64, 64), amdgpu_waves_per_eu(2, 2)))
void traj_kernel(
        const float* __restrict__ d_raw, const float* __restrict__ c_raw,
        const float* __restrict__ a_raw,
        uint_t* __restrict__ xout, int s_base) {
    const int li = blockIdx.x;
    const int s  = s_base + li;
    const int lane = threadIdx.x;
    const bool d1ok = lane < 63;                  // dim 2l+1 <= 126

    __shared__ __align__(16) float abuf[32][128]; // 16 KB (2 groups x 16 rows)
    __shared__ __align__(16) uint_t xstage[512];  // 2 KB (8 x-rows)
    __shared__ float  dls[128];
    __shared__ float2 cls2[128];

    // d (softplus'd), cos/sin tables for uniform broadcast reads (padded 0)
    float t0 = softplus_f(d_raw[(size_t)s * D_DIM + lane]);
    dls[lane] = t0;
    dls[64 + lane] = d1ok ? softplus_f(d_raw[(size_t)s * D_DIM + 64 + lane]) : 0.0f;
    {
        float cv = c_raw[(size_t)s * N_STEPS + lane];
        cls2[lane] = make_float2(__cosf(cv), __sinf(cv));
        if (lane < 62) {
            float cv2 = c_raw[(size_t)s * N_STEPS + 64 + lane];
            cls2[64 + lane] = make_float2(__cosf(cv2), __sinf(cv2));
        } else {
            cls2[64 + lane] = make_float2(0.0f, 0.0f);
        }
    }

    const float* ap = a_raw + (size_t)s * N_STEPS * D_DIM;
    uint_t* xg = xout + (size_t)li * NNODES * 64;

    // staging regs: one 16-row group
    float sa0, sa1, sa2, sa3, sa4, sa5, sa6, sa7,
          sa8, sa9, sa10, sa11, sa12, sa13, sa14, sa15;
    float sb0, sb1, sb2, sb3, sb4, sb5, sb6, sb7,
          sb8, sb9, sb10, sb11, sb12, sb13, sb14, sb15;

    // prologue: G0,G1 staged+written; G2 loaded (written at boundary g=0)
    LOAD_G(0, false)  WRITE_G(0)
    LOAD_G(16, false) WRITE_G(16)
    LOAD_G(32, false)

    // ring (rows i..i+3) + pipelines primed for steps 0,1
    float ra_r[4], rb_r[4];
    { float2 t = *(float2*)&abuf[0][2 * lane]; ra_r[0] = t.x; rb_r[0] = t.y; }
    { float2 t = *(float2*)&abuf[1][2 * lane]; ra_r[1] = t.x; rb_r[1] = t.y; }
    { float2 t = *(float2*)&abuf[2][2 * lane]; ra_r[2] = t.x; rb_r[2] = t.y; }
    ra_r[3] = 0.0f; rb_r[3] = 0.0f;
    float aaU = wave_sum(fmaf(ra_r[0], ra_r[0], rb_r[0] * rb_r[0]));
    float aa1 = wave_sum(fmaf(ra_r[1], ra_r[1], rb_r[1] * rb_r[1]));
    float aE0U = frl(ra_r[0], 0), aE1U = frl(rb_r[0], 0);
    float aE0_1 = frl(ra_r[1], 0), aE1_1 = frl(rb_r[1], 0);
    float cU, sU, c1, s1;
    { float2 cs = cls2[0]; cU = cs.x; sU = cs.y; }
    { float2 cs = cls2[1]; c1 = cs.x; s1 = cs.y; }
    float dU = dls[1], d1 = dls[2];

    // state: v (lane dims), replicated pivots, x
    float v0 = (lane == 0) ? 1.0f : 0.0f, v1 = 0.0f;
    float vp0 = 1.0f, vp1 = 0.0f, vp1s = 0.0f, rcp_v = 0.5f;
    float x0 = (lane == 0) ? t0 : 0.0f, x1 = 0.0f;

    // x rows 0,1 into staging slots 0,1
    xstage[lane] = 0u;
    {
        uint_t pk0;
        asm("v_cvt_pk_bf16_f32 %0, %1, %2" : "=v"(pk0) : "v"(x0), "v"(x1));
        xstage[64 + lane] = pk0;
    }

    // main: ROLLED loop, 31 iterations x 4 steps (i = 0..123).
    // Staging boundary every 16 steps at (q&3)==3; flush at i%8==5
    // (k==1, q odd). Small body fits I$.
    #pragma unroll 1
    for (int q = 0; q < 31; ++q) {
        const int i0 = q << 2;
        const bool fl = (q & 1) != 0;
        STEP_CORE(i0 + 0, 0, 2, 3, RR(i0 + 3), i0 + 2, i0 + 3, false)
        STEP_CORE(i0 + 1, 1, 3, 0, RR(i0 + 4), i0 + 3, i0 + 4, fl)
        STEP_CORE(i0 + 2, 2, 0, 1, RR(i0 + 5), i0 + 4, i0 + 5, false)
        STEP_CORE(i0 + 3, 3, 1, 2, RR(i0 + 6), i0 + 5, i0 + 6, false)
        if ((q & 3) == 3) {
            const int g = q >> 2;                 // 0..6
            if (g <= 5) { WRITE_G((g & 1) << 4) } // write G_{g+2}
            if (g <= 4) LOAD_G((g + 3) << 4, g == 4)  // load G_{g+3}
        }
    }
    // final steps 124, 125 (flush at 125 covers rows 120..127)
    STEP_CORE(124, 0, 2, 3, 125 & 31, 126, 127, false)
    STEP_CORE(125, 1, 3, 0, 125 & 31, 127, 127, true)
}
#undef RR
#undef STEP_CORE
#undef LOAD_G
#undef WRITE_G
#undef LDR1

// ---------------------------------------------------------------------------
// Kernel 2: MFMA gram (single 32KB bf16 LDS stage) + B-S tail log-lik.
// 4 waves; wave w owns tile-rows {w, 7-w} via template<int W> (acc = 9 f4).
// ---------------------------------------------------------------------------
__device__ __forceinline__ bfrag ldfrag(const ushort_t* base, int row, int kelem) {
    int byte = ((row << 8) + (kelem << 1)) ^ ((row & 7) << 4);
    return *(const bfrag*)((const char*)base + byte);
}

template<int W>
__device__ __forceinline__ void gram_w(const ushort_t* Xs, f4 (&acc)[9],
                                       int lr, int lg) {
    constexpr int RA = W, RB = 7 - W;
    #pragma unroll
    for (int ks = 0; ks < 4; ++ks) {
        const int kb = ks * 32 + lg * 8;
        const bfrag ha = ldfrag(Xs, RA * 16 + lr, kb);
        const bfrag hb = ldfrag(Xs, RB * 16 + lr, kb);
        #pragma unroll
        for (int TC = W; TC < 8; ++TC) {
            const bfrag bh = ldfrag(Xs, TC * 16 + lr, kb);
            acc[TC - W] = __builtin_amdgcn_mfma_f32_16x16x32_bf16(ha, bh, acc[TC - W], 0, 0, 0);
            if (TC >= RB)
                acc[TC + 1] = __builtin_amdgcn_mfma_f32_16x16x32_bf16(hb, bh, acc[TC + 1], 0, 0, 0);
        }
    }
}

template<int W>
__device__ __forceinline__ void write_sq(const f4 (&acc)[9], float* sq, int lr, int lg) {
    #pragma unroll
    for (int q = 0; q < 4; ++q) {
        if (4 * lg + q == lr) {
            sq[W * 16 + lr]       = acc[0][q];       // tile (W,W)
            sq[(7 - W) * 16 + lr] = acc[8 - W][q];   // tile (7-W,7-W)
        }
    }
}

// Borjesson-Sundberg Q(z) ~ phi(z)/((1-A)z + A*sqrt(z^2+B)); rel err <~0.5%.
// q_axb = F1 + F2 - 2 F1 F2 is relative-accurate (no cancellation).
__device__ __forceinline__ float entry_ll(float g, float sqn, float sqm,
        uint_t cw, float lam, float one_m2l) {
    const float d2 = fmaxf(sqn + sqm - 2.0f * g, 0.0f);
    const float pd = __builtin_amdgcn_sqrtf(d2);
    const float A = 0.344f, B = 5.334f, IA = 0.656f, C = 0.3989422804f;
    const float z1 = 0.70710678f * pd, z2 = 0.5f * pd;
    const float e1 = __expf(-0.25f  * d2) * C;   // phi(z1)
    const float e2 = __expf(-0.125f * d2) * C;   // phi(z2)
    const float den1 = fmaf(A, __builtin_amdgcn_sqrtf(fmaf(0.5f,  d2, B)), IA * z1);
    const float den2 = fmaf(A, __builtin_amdgcn_sqrtf(fmaf(0.25f, d2, B)), IA * z2);
    const float F1 = e1 * __builtin_amdgcn_rcpf(den1);
    const float F2 = e2 * __builtin_amdgcn_rcpf(den2);
    const float qax = F1 + F2 - 2.0f * F1 * F2;
    float qp = fmaf(one_m2l, qax, lam);
    qp = fminf(fmaxf(qp, 1e-7f), 1.0f - 1e-7f);
    const float pp = 1.0f - qp;
    const float c   = bf2f((ushort_t)(cw & 0xffffu));
    const float amc = bf2f((ushort_t)(cw >> 16));
    return c * __logf(pp) + amc * __logf(qp);
}

__device__ __forceinline__ float tile_ll(f4 a, int TR, int TC, bool diag,
        int lr, int lg, const float* sq, const uint_t* __restrict__ cnt,
        float lam, float one_m2l) {
    float s = 0.0f;
    #pragma unroll
    for (int q = 0; q < 4; ++q) {
        const int n = TR * 16 + 4 * lg + q;
        const int m = TC * 16 + lr;
        if (!diag || (4 * lg + q) <= lr)
            s += entry_ll(a[q], sq[n], sq[m], cnt[n * 128 + m], lam, one_m2l);
    }
    return s;
}

template<int W>
__device__ __forceinline__ float epi(const f4 (&acc)[9], const float* sq,
        const uint_t* __restrict__ cnt, int lr, int lg, float lam, float one_m2l) {
    constexpr int RA = W, RB = 7 - W;
    float s = 0.0f;
    #pragma unroll
    for (int TC = W; TC < 8; ++TC) {
        s += tile_ll(acc[TC - W], RA, TC, (TC == RA), lr, lg, sq, cnt, lam, one_m2l);
        if (TC >= RB)
            s += tile_ll(acc[TC + 1], RB, TC, (TC == RB), lr, lg, sq, cnt, lam, one_m2l);
    }
    return s;
}

__global__ __launch_bounds__(256, 4) void ll_kernel(
        const uint_t* __restrict__ x_g,
        const float* __restrict__ l_raw, const uint_t* __restrict__ cnt,
        float* __restrict__ sums, int s_base) {
    const int li = blockIdx.x;
    const int s  = s_base + li;
    const int t  = threadIdx.x;

    __shared__ __align__(16) ushort_t Xs[NNODES * 128];   // 32 KB
    __shared__ float sq[NNODES];
    __shared__ float wsum[4];

    const uint_t* gx = x_g + (size_t)li * NNODES * 64;
    const int l = t & 63, w = t >> 6, lr = l & 15, lg = l >> 4;

    // fill LDS (swizzled) with 16B chunks; 2048 chunks over 256 threads
    #pragma unroll
    for (int ii = 0; ii < 8; ++ii) {
        const int i = t + ii * 256;
        const int row = i >> 4, j = i & 15;
        const uint4 v = *(const uint4*)(gx + row * 64 + j * 4);
        const int b = ((row << 8) + (j << 4)) ^ ((row & 7) << 4);
        *(uint4*)((char*)Xs + b) = v;
    }
    __syncthreads();

    f4 acc[9];
    #pragma unroll
    for (int i = 0; i < 9; ++i) acc[i] = (f4)(0.0f);

    switch (w) {
        case 0: gram_w<0>(Xs, acc, lr, lg); write_sq<0>(acc, sq, lr, lg); break;
        case 1: gram_w<1>(Xs, acc, lr, lg); write_sq<1>(acc, sq, lr, lg); break;
        case 2: gram_w<2>(Xs, acc, lr, lg); write_sq<2>(acc, sq, lr, lg); break;
        default: gram_w<3>(Xs, acc, lr, lg); write_sq<3>(acc, sq, lr, lg); break;
    }
    __syncthreads();

    const float lam = 0.06f * normal_cdf_f(l_raw[s]);
    const float one_m2l = 1.0f - 2.0f * lam;
    float ll = 0.0f;
    switch (w) {
        case 0: ll = epi<0>(acc, sq, cnt, lr, lg, lam, one_m2l); break;
        case 1: ll = epi<1>(acc, sq, cnt, lr, lg, lam, one_m2l); break;
        case 2: ll = epi<2>(acc, sq, cnt, lr, lg, lam, one_m2l); break;
        default: ll = epi<3>(acc, sq, cnt, lr, lg, lam, one_m2l); break;
    }

    const float wtot = wave_sum(ll);
    if (l == 0) wsum[w] = wtot;
    __syncthreads();
    if (t == 0) sums[s] = wsum[0] + wsum[1] + wsum[2] + wsum[3];
}

// ---------------------------------------------------------------------------
// Kernel 3: deterministic mean over S
// ---------------------------------------------------------------------------
__global__ __launch_bounds__(256) void reduce_kernel(
        const float* __restrict__ sums, float* __restrict__ out) {
    __shared__ double sh[256];
    const int t = threadIdx.x;
    double acc = 0.0;
    for (int i = t; i < S_TOT; i += 256) acc += (double)sums[i];
    sh[t] = acc;
    __syncthreads();
    for (int off = 128; off > 0; off >>= 1) {
        if (t < off) sh[t] += sh[t + off];
        __syncthreads();
    }
    if (t == 0) out[0] = (float)(sh[0] / (double)S_TOT);
}

// ---------------------------------------------------------------------------
extern "C" void kernel_launch(void* const* d_in, const int* in_sizes, int n_in,
                              void* d_out, int out_size, void* d_ws, size_t ws_size,
                              hipStream_t stream) {
    (void)in_sizes; (void)n_in; (void)out_size;
    const float* d_raw = (const float*)d_in[0];
    const float* c_raw = (const float*)d_in[1];
    const float* a_raw = (const float*)d_in[2];
    const float* l_raw = (const float*)d_in[3];
    const int*   all_t = (const int*)d_in[4];
    const int*   cor_t = (const int*)d_in[5];
    float* out = (float*)d_out;

    char*   ws   = (char*)d_ws;
    float*  sums = (float*)ws;                        // 8 KB
    uint_t* cnt  = (uint_t*)(ws + 8192);              // 64 KB packed counts
    char*   xbase = ws + 8192 + 65536;
    const size_t per_sample = (size_t)NNODES * 64 * sizeof(uint_t);  // 32 KB

    const size_t head = 8192 + 65536;
    size_t avail = (ws_size > head) ? ws_size - head : 0;
    int chunk = (int)(avail / per_sample);
    if (chunk > S_TOT) chunk = S_TOT;
    if (chunk < 1) chunk = 1;

    prep_counts<<<64, 256, 0, stream>>>(all_t, cor_t, cnt);

    for (int s0 = 0; s0 < S_TOT; s0 += chunk) {
        const int nblk = (S_TOT - s0 < chunk) ? (S_TOT - s0) : chunk;
        uint_t* xbuf = (uint_t*)xbase;
        traj_kernel<<<nblk, 64, 0, stream>>>(d_raw, c_raw, a_raw, xbuf, s0);
        ll_kernel<<<nblk, 256, 0, stream>>>(xbuf, l_raw, cnt, sums, s0);
    }
    reduce_kernel<<<1, 256, 0, stream>>>(sums, out);
}